// Round 8
// baseline (334.696 us; speedup 1.0000x reference)
//
#include <hip/hip_runtime.h>
#include <hip/hip_bf16.h>
#include <math.h>

#define NB   8
#define SEQ  1024
#define DIMS 1024
#define NH   16
#define HD   64
#define MROWS (NB*SEQ)   // 8192

typedef unsigned short u16;
typedef short short8 __attribute__((ext_vector_type(8)));
typedef short short4v __attribute__((ext_vector_type(4)));
typedef float f32x4 __attribute__((ext_vector_type(4)));
typedef float f32x16 __attribute__((ext_vector_type(16)));

extern "C" __device__ float __ocml_native_exp2_f32(float);   // bare v_exp_f32

__device__ inline u16 f2bf(float f) {
    unsigned u = __float_as_uint(f);
    u += 0x7fff + ((u >> 16) & 1);   // RNE
    return (u16)(u >> 16);
}

__device__ inline unsigned pkbf(float a, float b) {
    float2 f2; f2.x = a; f2.y = b;
    __hip_bfloat162 h = __float22bfloat162_rn(f2);
    return *reinterpret_cast<unsigned*>(&h);
}

#define MFMA16(a, b, c) __builtin_amdgcn_mfma_f32_16x16x32_bf16((a), (b), (c), 0, 0, 0)
#define MFMA32(a, b, c) __builtin_amdgcn_mfma_f32_32x32x16_bf16((a), (b), (c), 0, 0, 0)
#define GLD16(g, l) __builtin_amdgcn_global_load_lds( \
    (const __attribute__((address_space(1))) void*)(g), \
    (__attribute__((address_space(3))) void*)(l), 16, 0, 0)

// ---------------------------------------------------------------------------
// fp32 -> bf16 elementwise (8 elems/thread)
// ---------------------------------------------------------------------------
__global__ __launch_bounds__(256)
void convert_bf16(const float* __restrict__ in, u16* __restrict__ out, int n8)
{
    int i = blockIdx.x * 256 + threadIdx.x;
    if (i >= n8) return;
    float4 v0 = ((const float4*)in)[2 * i];
    float4 v1 = ((const float4*)in)[2 * i + 1];
    union { short8 s; u16 u[8]; } r;
    r.u[0] = f2bf(v0.x); r.u[1] = f2bf(v0.y); r.u[2] = f2bf(v0.z); r.u[3] = f2bf(v0.w);
    r.u[4] = f2bf(v1.x); r.u[5] = f2bf(v1.y); r.u[6] = f2bf(v1.z); r.u[7] = f2bf(v1.w);
    ((short8*)out)[i] = r.s;
}

// ---------------------------------------------------------------------------
// W[k][n] fp32 -> Wt[n][k] bf16 (64x64 tiles, grid 256)
// ---------------------------------------------------------------------------
__global__ __launch_bounds__(256)
void transpose_convert(const float* __restrict__ W, u16* __restrict__ Wt)
{
    __shared__ u16 T[64][72];
    const int t  = threadIdx.x;
    const int k0 = (blockIdx.x >> 4) * 64;
    const int n0 = (blockIdx.x & 15) * 64;
    #pragma unroll
    for (int it = 0; it < 4; ++it) {
        int f  = t + it * 256;
        int kl = f >> 4;
        int n4 = (f & 15) * 4;
        float4 v = *(const float4*)&W[(size_t)(k0 + kl) * DIMS + n0 + n4];
        T[n4 + 0][kl] = f2bf(v.x);
        T[n4 + 1][kl] = f2bf(v.y);
        T[n4 + 2][kl] = f2bf(v.z);
        T[n4 + 3][kl] = f2bf(v.w);
    }
    __syncthreads();
    #pragma unroll
    for (int it = 0; it < 2; ++it) {
        int c  = t + it * 256;
        int nl = c >> 3;
        int k8 = (c & 7) * 8;
        *(short8*)&Wt[(size_t)(n0 + nl) * DIMS + k0 + k8] = *(const short8*)&T[nl][k8];
    }
}

// ---------------------------------------------------------------------------
// bf16 MFMA GEMM: C = A @ Bt^T + bias.  A:[m][k] bf16, Bt:[n][k] bf16.
// 128x128 tile, BK=64, 4 waves, global_load_lds staging.
// MODE 0: fp32 row-major; MODE 1: bf16 (acc+bias)*scale scatter [b][h][p][d];
// MODE 2: bf16 scatter-transpose [b][h][d][p]
// ---------------------------------------------------------------------------
template<int MODE>
__global__ __launch_bounds__(256)
void gemm_bf16(const u16* __restrict__ A, const u16* __restrict__ Bt,
               const float* __restrict__ bias, void* __restrict__ Cout, float scale)
{
    __shared__ u16 sm[17408];
    u16* As = sm;
    u16* Bs = sm + 8192;

    const int t    = threadIdx.x;
    const int w    = t >> 6, lane = t & 63;
    const int lo   = lane & 15, hi = lane >> 4;
    const int bn   = blockIdx.x & 7;
    const int bm   = blockIdx.x >> 3;
    const int m0   = bm * 128, n0 = bn * 128;
    const int wm   = (w >> 1) * 64, wn = (w & 1) * 64;

    f32x4 acc[4][4];
    #pragma unroll
    for (int mf = 0; mf < 4; ++mf)
        #pragma unroll
        for (int nf = 0; nf < 4; ++nf) acc[mf][nf] = (f32x4){0.f, 0.f, 0.f, 0.f};

    const u16* ga[4]; const u16* gb[4]; u16* la[4]; u16* lb[4];
    #pragma unroll
    for (int i = 0; i < 4; ++i) {
        int c   = (w * 4 + i) * 64 + lane;
        int row = c >> 3, kc = c & 7;
        ga[i] = A  + (size_t)(m0 + row) * 1024 + kc * 8;
        gb[i] = Bt + (size_t)(n0 + row) * 1024 + kc * 8;
        la[i] = As + (w * 4 + i) * 512;
        lb[i] = Bs + (w * 4 + i) * 512;
    }

    for (int kt = 0; kt < 16; ++kt) {
        if (kt) __syncthreads();
        #pragma unroll
        for (int i = 0; i < 4; ++i) {
            GLD16(ga[i] + kt * 64, la[i]);
            GLD16(gb[i] + kt * 64, lb[i]);
        }
        __syncthreads();

        #pragma unroll
        for (int s = 0; s < 2; ++s) {
            short8 fa[4], fb[4];
            #pragma unroll
            for (int mf = 0; mf < 4; ++mf)
                fa[mf] = *(const short8*)&As[(wm + mf * 16 + lo) * 64 + s * 32 + hi * 8];
            #pragma unroll
            for (int nf = 0; nf < 4; ++nf)
                fb[nf] = *(const short8*)&Bs[(wn + nf * 16 + lo) * 64 + s * 32 + hi * 8];
            #pragma unroll
            for (int mf = 0; mf < 4; ++mf)
                #pragma unroll
                for (int nf = 0; nf < 4; ++nf)
                    acc[mf][nf] = MFMA16(fa[mf], fb[nf], acc[mf][nf]);
        }
    }

    if (MODE == 0) {
        float* out = (float*)Cout;
        #pragma unroll
        for (int mf = 0; mf < 4; ++mf)
            #pragma unroll
            for (int j = 0; j < 4; ++j) {
                int r = m0 + wm + mf * 16 + hi * 4 + j;
                #pragma unroll
                for (int nf = 0; nf < 4; ++nf) {
                    int cc = n0 + wn + nf * 16 + lo;
                    out[(size_t)r * 1024 + cc] = acc[mf][nf][j] + bias[cc];
                }
            }
        return;
    }

    __syncthreads();
    if (MODE == 1) {
        #pragma unroll
        for (int mf = 0; mf < 4; ++mf)
            #pragma unroll
            for (int j = 0; j < 4; ++j) {
                int pl = wm + mf * 16 + hi * 4 + j;
                #pragma unroll
                for (int nf = 0; nf < 4; ++nf) {
                    int nl = wn + nf * 16 + lo;
                    int h = nl & 15, dl = nl >> 4;
                    float v = (acc[mf][nf][j] + bias[n0 + nl]) * scale;
                    sm[pl * 136 + h * 8 + dl] = f2bf(v);
                }
            }
        __syncthreads();
        u16* out = (u16*)Cout;
        const int bb = m0 >> 10, p0 = m0 & 1023, dg = n0 >> 4;
        #pragma unroll
        for (int it = 0; it < 8; ++it) {
            int c = t + it * 256;
            int h = c & 15, pl = c >> 4;
            u16* dst = out + ((size_t)((bb * NH + h) * SEQ + p0 + pl)) * HD + dg;
            *(short8*)dst = *(const short8*)&sm[pl * 136 + h * 8];
        }
    } else {
        #pragma unroll
        for (int mf = 0; mf < 4; ++mf)
            #pragma unroll
            for (int j = 0; j < 4; ++j) {
                int pl = wm + mf * 16 + hi * 4 + j;
                #pragma unroll
                for (int nf = 0; nf < 4; ++nf) {
                    int nl = wn + nf * 16 + lo;
                    sm[nl * 136 + pl] = f2bf(acc[mf][nf][j] + bias[n0 + nl]);
                }
            }
        __syncthreads();
        u16* out = (u16*)Cout;
        const int bb = m0 >> 10, p0 = m0 & 1023;
        #pragma unroll
        for (int it = 0; it < 8; ++it) {
            int c  = t + it * 256;
            int nl = c >> 4, p8 = c & 15;
            int ng = n0 + nl;
            int h = ng & 15, d = ng >> 4;
            u16* dst = out + ((size_t)((bb * NH + h) * HD + d)) * SEQ + p0 + p8 * 8;
            *(short8*)dst = *(const short8*)&sm[nl * 136 + p8 * 8];
        }
    }
}

// ---------------------------------------------------------------------------
// Swapped-operand 32x32x16 MFMA flash attention, zero-LDS zero-shuffle loop,
// SOFTWARE-PIPELINED: 32-kv half-tiles; K regs reloaded for h+1 right after
// the QK MFMAs consume them (latency hidden under exp2+pack+PV), V regs
// reloaded at body end (hidden under next half-tile's QK+exp2). Single
// buffers, all indices compile-time. Unshifted softmax P = exp2(s); scale
// cancels exactly in O/l. Final prefetch (h=32) reads a few KB into the
// adjacent workspace region — allocated, never used.
// ---------------------------------------------------------------------------
__global__ __launch_bounds__(256, 4)
void attn_mfma32_kernel(const u16* __restrict__ Qm, const u16* __restrict__ Km,
                        const u16* __restrict__ Vt, u16* __restrict__ heads)
{
    __shared__ u16 Os[4][32][68];   // epilogue transpose only

    const int t  = threadIdx.x;
    const int w  = t >> 6, l = t & 63;
    const int ql = l & 31, h5 = l >> 5;

    // XCD-aware bijective swizzle (nwg=1024, 8 XCDs): qb innermost per XCD
    const int wg  = blockIdx.x;
    const int swz = (wg & 7) * 128 + (wg >> 3);
    const int qb  = swz & 7;
    const int bh  = swz >> 3;
    const int q0 = qb * 128 + w * 32;
    const size_t kbase = (size_t)bh * (SEQ * HD);
    const size_t vbase = (size_t)bh * (HD * SEQ);

    // Q B-fragments: lane holds Q[q0+ql][d = td*16 + h5*8 + 0..7]
    short8 qf[4];
    #pragma unroll
    for (int td = 0; td < 4; ++td)
        qf[td] = *(const short8*)&Qm[kbase + (size_t)(q0 + ql) * HD + td * 16 + h5 * 8];

    // per-lane base pointers
    const u16* pk  = Km + kbase + (size_t)ql * HD + h5 * 8;   // K row ql (+32/half-tile)
    const u16* pv0 = Vt + vbase + (size_t)ql * SEQ + 4 * h5;  // V^T row d=ql
    const u16* pv1 = pv0 + 32 * SEQ;                          // d=32+ql

    union S8V { short4v h[2]; short8 s; };
    short8 kR[4];
    S8V    vR[4];

#define LOADK(H) { const u16* p = pk + (size_t)(H) * 32 * HD;                       \
    kR[0] = *(const short8*)&p[0];  kR[1] = *(const short8*)&p[16];                 \
    kR[2] = *(const short8*)&p[32]; kR[3] = *(const short8*)&p[48]; }
#define LOADV(H) { const u16* p0 = pv0 + (H) * 32; const u16* p1 = pv1 + (H) * 32;  \
    vR[0].h[0] = *(const short4v*)&p0[0];  vR[0].h[1] = *(const short4v*)&p0[8];    \
    vR[1].h[0] = *(const short4v*)&p0[16]; vR[1].h[1] = *(const short4v*)&p0[24];   \
    vR[2].h[0] = *(const short4v*)&p1[0];  vR[2].h[1] = *(const short4v*)&p1[8];    \
    vR[3].h[0] = *(const short4v*)&p1[16]; vR[3].h[1] = *(const short4v*)&p1[24]; }

    f32x16 o0, o1;
    #pragma unroll
    for (int i = 0; i < 16; ++i) { o0[i] = 0.f; o1[i] = 0.f; }
    float ls0 = 0.f, ls1 = 0.f, ls2 = 0.f, ls3 = 0.f;

    LOADK(0); LOADV(0);

    for (int h = 0; h < 32; ++h) {
        // ---- scores: one 32x32 tile (kv = h*32 .. +32), log2 domain ----
        f32x16 sc;
        #pragma unroll
        for (int i = 0; i < 16; ++i) sc[i] = 0.f;
        sc = MFMA32(kR[0], qf[0], sc);
        sc = MFMA32(kR[1], qf[1], sc);
        sc = MFMA32(kR[2], qf[2], sc);
        sc = MFMA32(kR[3], qf[3], sc);

        // kR consumed -> reload for next half-tile (latency hides below)
        LOADK(h + 1);

        // ---- P = exp2(s), 4-way partial l accumulation ----
        #pragma unroll
        for (int i = 0; i < 16; i += 4) {
            float p0 = __ocml_native_exp2_f32(sc[i + 0]);
            float p1 = __ocml_native_exp2_f32(sc[i + 1]);
            float p2 = __ocml_native_exp2_f32(sc[i + 2]);
            float p3 = __ocml_native_exp2_f32(sc[i + 3]);
            sc[i + 0] = p0; sc[i + 1] = p1; sc[i + 2] = p2; sc[i + 3] = p3;
            ls0 += p0; ls1 += p1; ls2 += p2; ls3 += p3;
        }

        // ---- pack P in register order (contraction-permutation trick) ----
        union { unsigned u[4]; short8 s; } pb0, pb1;
        pb0.u[0] = pkbf(sc[0],  sc[1]);  pb0.u[1] = pkbf(sc[2],  sc[3]);
        pb0.u[2] = pkbf(sc[4],  sc[5]);  pb0.u[3] = pkbf(sc[6],  sc[7]);
        pb1.u[0] = pkbf(sc[8],  sc[9]);  pb1.u[1] = pkbf(sc[10], sc[11]);
        pb1.u[2] = pkbf(sc[12], sc[13]); pb1.u[3] = pkbf(sc[14], sc[15]);

        // ---- O^T += V^T P ----
        o0 = MFMA32(vR[0].s, pb0.s, o0);
        o0 = MFMA32(vR[1].s, pb1.s, o0);
        o1 = MFMA32(vR[2].s, pb0.s, o1);
        o1 = MFMA32(vR[3].s, pb1.s, o1);

        // vR consumed -> reload for next half-tile (hides under next QK+exp2)
        LOADV(h + 1);
    }

    // ---- finalize: l total (own half + partner half), O /= l, transpose ----
    float l_run = (ls0 + ls1) + (ls2 + ls3);
    float l_tot = l_run + __shfl_xor(l_run, 32);
    float inv = 1.0f / l_tot;
    #pragma unroll
    for (int r = 0; r < 16; r += 2) {
        int d = (r & 3) + 8 * (r >> 2) + 4 * h5;
        *(unsigned*)&Os[w][ql][d]      = pkbf(o0[r] * inv, o0[r + 1] * inv);
        *(unsigned*)&Os[w][ql][32 + d] = pkbf(o1[r] * inv, o1[r + 1] * inv);
    }
    __syncthreads();
    const int bb = bh >> 4, h = bh & 15;
    #pragma unroll
    for (int i = 0; i < 4; ++i) {
        int d = h5 * 32 + i * 8;
        short8 vv = *(const short8*)&Os[w][ql][d];
        *(short8*)&heads[((size_t)(bb * SEQ + q0 + ql) * NH + h) * HD + d] = vv;
    }
#undef LOADK
#undef LOADV
}

// ---------------------------------------------------------------------------
extern "C" void kernel_launch(void* const* d_in, const int* in_sizes, int n_in,
                              void* d_out, int out_size, void* d_ws, size_t ws_size,
                              hipStream_t stream) {
    const float* q  = (const float*)d_in[0];
    const float* x  = (const float*)d_in[1];
    const float* Wq = (const float*)d_in[2];
    const float* bq = (const float*)d_in[3];
    const float* Wk = (const float*)d_in[4];
    const float* bk = (const float*)d_in[5];
    const float* Wv = (const float*)d_in[6];
    const float* bv = (const float*)d_in[7];
    const float* Wp = (const float*)d_in[8];
    const float* bp = (const float*)d_in[9];
    float* out = (float*)d_out;

    const size_t SZ = (size_t)MROWS * DIMS;
    const size_t WZ = (size_t)DIMS * DIMS;
    u16* qb  = (u16*)d_ws;
    u16* xb  = qb  + SZ;
    u16* Wqt = xb  + SZ;
    u16* Wkt = Wqt + WZ;
    u16* Wvt = Wkt + WZ;
    u16* Wpt = Wvt + WZ;
    u16* Qm  = Wpt + WZ;
    u16* Km  = Qm  + SZ;
    u16* Vm  = Km  + SZ;
    u16* Hm  = Vm  + SZ;

    dim3 blk(256);
    const int n8 = (int)(SZ / 8);

    hipLaunchKernelGGL(convert_bf16, dim3(n8 / 256), blk, 0, stream, q, qb, n8);
    hipLaunchKernelGGL(convert_bf16, dim3(n8 / 256), blk, 0, stream, x, xb, n8);
    hipLaunchKernelGGL(transpose_convert, dim3(256), blk, 0, stream, Wq, Wqt);
    hipLaunchKernelGGL(transpose_convert, dim3(256), blk, 0, stream, Wk, Wkt);
    hipLaunchKernelGGL(transpose_convert, dim3(256), blk, 0, stream, Wv, Wvt);
    hipLaunchKernelGGL(transpose_convert, dim3(256), blk, 0, stream, Wp, Wpt);

    dim3 gemm_grid(512);
    const float qscale = 0.125f * 1.4426950408889634f;   // log2 domain
    hipLaunchKernelGGL((gemm_bf16<1>), gemm_grid, blk, 0, stream, qb, Wqt, bq, (void*)Qm, qscale);
    hipLaunchKernelGGL((gemm_bf16<1>), gemm_grid, blk, 0, stream, xb, Wkt, bk, (void*)Km, 1.0f);
    hipLaunchKernelGGL((gemm_bf16<2>), gemm_grid, blk, 0, stream, xb, Wvt, bv, (void*)Vm, 1.0f);

    dim3 attn_grid(NB * NH * (SEQ / 128));  // 1024
    hipLaunchKernelGGL(attn_mfma32_kernel, attn_grid, blk, 0, stream, Qm, Km, Vm, Hm);

    hipLaunchKernelGGL((gemm_bf16<0>), gemm_grid, blk, 0, stream, Hm, Wpt, bp, (void*)out, 1.0f);
}

// Round 9
// 208.452 us; speedup vs baseline: 1.6056x; 1.6056x over previous
//
#include <hip/hip_runtime.h>
#include <hip/hip_bf16.h>
#include <math.h>

#define NB   8
#define SEQ  1024
#define DIMS 1024
#define NH   16
#define HD   64
#define MROWS (NB*SEQ)   // 8192

typedef unsigned short u16;
typedef short short8 __attribute__((ext_vector_type(8)));
typedef short short4v __attribute__((ext_vector_type(4)));
typedef float f32x4 __attribute__((ext_vector_type(4)));
typedef float f32x16 __attribute__((ext_vector_type(16)));

extern "C" __device__ float __ocml_native_exp2_f32(float);   // bare v_exp_f32

__device__ inline u16 f2bf(float f) {
    unsigned u = __float_as_uint(f);
    u += 0x7fff + ((u >> 16) & 1);   // RNE
    return (u16)(u >> 16);
}

__device__ inline unsigned pkbf(float a, float b) {
    float2 f2; f2.x = a; f2.y = b;
    __hip_bfloat162 h = __float22bfloat162_rn(f2);
    return *reinterpret_cast<unsigned*>(&h);
}

#define MFMA16(a, b, c) __builtin_amdgcn_mfma_f32_16x16x32_bf16((a), (b), (c), 0, 0, 0)
#define MFMA32(a, b, c) __builtin_amdgcn_mfma_f32_32x32x16_bf16((a), (b), (c), 0, 0, 0)
#define GLD16(g, l) __builtin_amdgcn_global_load_lds( \
    (const __attribute__((address_space(1))) void*)(g), \
    (__attribute__((address_space(3))) void*)(l), 16, 0, 0)

// ---------------------------------------------------------------------------
// fp32 -> bf16 elementwise (8 elems/thread)
// ---------------------------------------------------------------------------
__global__ __launch_bounds__(256)
void convert_bf16(const float* __restrict__ in, u16* __restrict__ out, int n8)
{
    int i = blockIdx.x * 256 + threadIdx.x;
    if (i >= n8) return;
    float4 v0 = ((const float4*)in)[2 * i];
    float4 v1 = ((const float4*)in)[2 * i + 1];
    union { short8 s; u16 u[8]; } r;
    r.u[0] = f2bf(v0.x); r.u[1] = f2bf(v0.y); r.u[2] = f2bf(v0.z); r.u[3] = f2bf(v0.w);
    r.u[4] = f2bf(v1.x); r.u[5] = f2bf(v1.y); r.u[6] = f2bf(v1.z); r.u[7] = f2bf(v1.w);
    ((short8*)out)[i] = r.s;
}

// ---------------------------------------------------------------------------
// W[k][n] fp32 -> Wt[n][k] bf16 (64x64 tiles, grid 256)
// ---------------------------------------------------------------------------
__global__ __launch_bounds__(256)
void transpose_convert(const float* __restrict__ W, u16* __restrict__ Wt)
{
    __shared__ u16 T[64][72];
    const int t  = threadIdx.x;
    const int k0 = (blockIdx.x >> 4) * 64;
    const int n0 = (blockIdx.x & 15) * 64;
    #pragma unroll
    for (int it = 0; it < 4; ++it) {
        int f  = t + it * 256;
        int kl = f >> 4;
        int n4 = (f & 15) * 4;
        float4 v = *(const float4*)&W[(size_t)(k0 + kl) * DIMS + n0 + n4];
        T[n4 + 0][kl] = f2bf(v.x);
        T[n4 + 1][kl] = f2bf(v.y);
        T[n4 + 2][kl] = f2bf(v.z);
        T[n4 + 3][kl] = f2bf(v.w);
    }
    __syncthreads();
    #pragma unroll
    for (int it = 0; it < 2; ++it) {
        int c  = t + it * 256;
        int nl = c >> 3;
        int k8 = (c & 7) * 8;
        *(short8*)&Wt[(size_t)(n0 + nl) * DIMS + k0 + k8] = *(const short8*)&T[nl][k8];
    }
}

// ---------------------------------------------------------------------------
// bf16 MFMA GEMM: C = A @ Bt^T + bias.  A:[m][k] bf16, Bt:[n][k] bf16.
// 128x128 tile, BK=64, 4 waves, global_load_lds staging.
// MODE 0: fp32 row-major; MODE 1: bf16 (acc+bias)*scale scatter [b][h][p][d];
// MODE 2: bf16 scatter-transpose [b][h][d][p] with kv-pi-permutation
//         (within each 16-group, 4-elem chunks stored in order g0,g2,g1,g3)
// ---------------------------------------------------------------------------
template<int MODE>
__global__ __launch_bounds__(256)
void gemm_bf16(const u16* __restrict__ A, const u16* __restrict__ Bt,
               const float* __restrict__ bias, void* __restrict__ Cout, float scale)
{
    __shared__ u16 sm[17408];
    u16* As = sm;
    u16* Bs = sm + 8192;

    const int t    = threadIdx.x;
    const int w    = t >> 6, lane = t & 63;
    const int lo   = lane & 15, hi = lane >> 4;
    const int bn   = blockIdx.x & 7;
    const int bm   = blockIdx.x >> 3;
    const int m0   = bm * 128, n0 = bn * 128;
    const int wm   = (w >> 1) * 64, wn = (w & 1) * 64;

    f32x4 acc[4][4];
    #pragma unroll
    for (int mf = 0; mf < 4; ++mf)
        #pragma unroll
        for (int nf = 0; nf < 4; ++nf) acc[mf][nf] = (f32x4){0.f, 0.f, 0.f, 0.f};

    const u16* ga[4]; const u16* gb[4]; u16* la[4]; u16* lb[4];
    #pragma unroll
    for (int i = 0; i < 4; ++i) {
        int c   = (w * 4 + i) * 64 + lane;
        int row = c >> 3, kc = c & 7;
        ga[i] = A  + (size_t)(m0 + row) * 1024 + kc * 8;
        gb[i] = Bt + (size_t)(n0 + row) * 1024 + kc * 8;
        la[i] = As + (w * 4 + i) * 512;
        lb[i] = Bs + (w * 4 + i) * 512;
    }

    for (int kt = 0; kt < 16; ++kt) {
        if (kt) __syncthreads();
        #pragma unroll
        for (int i = 0; i < 4; ++i) {
            GLD16(ga[i] + kt * 64, la[i]);
            GLD16(gb[i] + kt * 64, lb[i]);
        }
        __syncthreads();

        #pragma unroll
        for (int s = 0; s < 2; ++s) {
            short8 fa[4], fb[4];
            #pragma unroll
            for (int mf = 0; mf < 4; ++mf)
                fa[mf] = *(const short8*)&As[(wm + mf * 16 + lo) * 64 + s * 32 + hi * 8];
            #pragma unroll
            for (int nf = 0; nf < 4; ++nf)
                fb[nf] = *(const short8*)&Bs[(wn + nf * 16 + lo) * 64 + s * 32 + hi * 8];
            #pragma unroll
            for (int mf = 0; mf < 4; ++mf)
                #pragma unroll
                for (int nf = 0; nf < 4; ++nf)
                    acc[mf][nf] = MFMA16(fa[mf], fb[nf], acc[mf][nf]);
        }
    }

    if (MODE == 0) {
        float* out = (float*)Cout;
        #pragma unroll
        for (int mf = 0; mf < 4; ++mf)
            #pragma unroll
            for (int j = 0; j < 4; ++j) {
                int r = m0 + wm + mf * 16 + hi * 4 + j;
                #pragma unroll
                for (int nf = 0; nf < 4; ++nf) {
                    int cc = n0 + wn + nf * 16 + lo;
                    out[(size_t)r * 1024 + cc] = acc[mf][nf][j] + bias[cc];
                }
            }
        return;
    }

    __syncthreads();
    if (MODE == 1) {
        #pragma unroll
        for (int mf = 0; mf < 4; ++mf)
            #pragma unroll
            for (int j = 0; j < 4; ++j) {
                int pl = wm + mf * 16 + hi * 4 + j;
                #pragma unroll
                for (int nf = 0; nf < 4; ++nf) {
                    int nl = wn + nf * 16 + lo;
                    int h = nl & 15, dl = nl >> 4;
                    float v = (acc[mf][nf][j] + bias[n0 + nl]) * scale;
                    sm[pl * 136 + h * 8 + dl] = f2bf(v);
                }
            }
        __syncthreads();
        u16* out = (u16*)Cout;
        const int bb = m0 >> 10, p0 = m0 & 1023, dg = n0 >> 4;
        #pragma unroll
        for (int it = 0; it < 8; ++it) {
            int c = t + it * 256;
            int h = c & 15, pl = c >> 4;
            u16* dst = out + ((size_t)((bb * NH + h) * SEQ + p0 + pl)) * HD + dg;
            *(short8*)dst = *(const short8*)&sm[pl * 136 + h * 8];
        }
    } else {
        #pragma unroll
        for (int mf = 0; mf < 4; ++mf)
            #pragma unroll
            for (int j = 0; j < 4; ++j) {
                int pl = wm + mf * 16 + hi * 4 + j;
                #pragma unroll
                for (int nf = 0; nf < 4; ++nf) {
                    int nl = wn + nf * 16 + lo;
                    sm[nl * 136 + pl] = f2bf(acc[mf][nf][j] + bias[n0 + nl]);
                }
            }
        __syncthreads();
        u16* out = (u16*)Cout;
        const int bb = m0 >> 10, p0 = m0 & 1023;
        #pragma unroll
        for (int it = 0; it < 8; ++it) {
            int c  = t + it * 256;
            int nl = c >> 4, p8 = c & 15;
            int ng = n0 + nl;
            int h = ng & 15, d = ng >> 4;
            u16* dstrow = out + ((size_t)((bb * NH + h) * HD + d)) * SEQ + p0;
            const u16* src = &sm[nl * 136 + p8 * 8];
            // pi-permute: 4-elem group g in 16-block -> slot ((g&1)<<1)|(g>>1)
            int base16 = (p8 >> 1) * 16, c8 = p8 & 1;
            *(short4v*)&dstrow[base16 + c8 * 4]     = *(const short4v*)&src[0];
            *(short4v*)&dstrow[base16 + c8 * 4 + 8] = *(const short4v*)&src[4];
        }
    }
}

// ---------------------------------------------------------------------------
// LDS-staged swapped-operand 32x32x16 MFMA flash attention.
// Block = 512 thr / 8 waves = one (b,h) x 256 q-rows; wave owns 32 q.
// Per 64-kv tile: K (8KB) + V^T (8KB) staged via one global_load_lds x16B per
// thread each, double-buffered (2-phase pipeline, one barrier per tile).
// XOR-swizzled LDS (byte ^= (row&7)<<4) via pre-swizzled global source;
// fragment reads are ds_read_b128 at loop-invariant offsets (4-way residual).
// Unshifted softmax P = exp2(s_log2) — scale cancels exactly in O/l.
// PV contraction pre-permuted (pi baked into V^T global layout by MODE 2).
// ---------------------------------------------------------------------------
__global__ __launch_bounds__(512, 4)
void attn_mfma32_kernel(const u16* __restrict__ Qm, const u16* __restrict__ Km,
                        const u16* __restrict__ Vp, u16* __restrict__ heads)
{
    __shared__ u16 KV[2][8192];   // [buf][ K:0..4095 | V:4096..8191 ]  32KB

    const int t  = threadIdx.x;          // 0..511
    const int w  = t >> 6, lane = t & 63;
    const int ql = lane & 31, h5 = lane >> 5;

    // XCD-aware bijective swizzle (nwg=512, 8 XCDs), qb innermost
    const int wg  = blockIdx.x;
    const int swz = (wg & 7) * 64 + (wg >> 3);
    const int qb  = swz & 3;
    const int bh  = swz >> 2;
    const int q0  = qb * 256 + w * 32;
    const size_t kbase = (size_t)bh * (SEQ * HD);
    const size_t vbase = (size_t)bh * (HD * SEQ);

    // staging: thread t owns 16B chunk t; global source is inverse-swizzled
    const int lc = t ^ ((t >> 3) & 7);
    const u16* gK = Km + kbase + (size_t)lc * 8;                       // tile-contig
    const u16* gV = Vp + vbase + (size_t)(t >> 3) * SEQ + (lc & 7) * 8; // row stride SEQ
    const int ldK = w * 512;          // wave-uniform LDS dest (u16 idx)
    const int ldV = 4096 + w * 512;

#define STAGE(B, T) do { \
    GLD16(gK + (size_t)(T) * 4096, &KV[B][ldK]); \
    GLD16(gV + (T) * 64,           &KV[B][ldV]); } while (0)

    STAGE(0, 0);

    // Q B-fragments: lane holds Q[q0+ql][d = td*16 + h5*8 + 0..7]
    short8 qf[4];
    #pragma unroll
    for (int td = 0; td < 4; ++td)
        qf[td] = *(const short8*)&Qm[kbase + (size_t)(q0 + ql) * HD + td * 16 + h5 * 8];

    // loop-invariant swizzled LDS offsets (u16 units)
    const int sw0 = (ql & 7) << 3;
    const int rb0 = ql * 64, rb1 = (32 + ql) * 64;
    int kof[4], vof[4];
    #pragma unroll
    for (int i = 0; i < 4; ++i) {
        kof[i] = (i * 16 + h5 * 8) ^ sw0;
        vof[i] = (i * 16 + h5 * 8) ^ sw0;
    }

    f32x16 o0, o1;
    #pragma unroll
    for (int i = 0; i < 16; ++i) { o0[i] = 0.f; o1[i] = 0.f; }
    float ls0 = 0.f, ls1 = 0.f, ls2 = 0.f, ls3 = 0.f;

    __syncthreads();   // tile 0 staged (implicit vmcnt drain)

    for (int tile = 0; tile < 16; ++tile) {
        const int buf = tile & 1;
        if (tile < 15) STAGE(buf ^ 1, tile + 1);

        const u16* Kb = &KV[buf][0];
        const u16* Vb = &KV[buf][4096];

        // ---- QK: two 32x32 score tiles (log2 domain) ----
        f32x16 sc0, sc1;
        #pragma unroll
        for (int i = 0; i < 16; ++i) { sc0[i] = 0.f; sc1[i] = 0.f; }
        {
            short8 k0 = *(const short8*)&Kb[rb0 + kof[0]];
            short8 k1 = *(const short8*)&Kb[rb0 + kof[1]];
            short8 k2 = *(const short8*)&Kb[rb0 + kof[2]];
            short8 k3 = *(const short8*)&Kb[rb0 + kof[3]];
            sc0 = MFMA32(k0, qf[0], sc0);
            sc0 = MFMA32(k1, qf[1], sc0);
            sc0 = MFMA32(k2, qf[2], sc0);
            sc0 = MFMA32(k3, qf[3], sc0);
            short8 m0_ = *(const short8*)&Kb[rb1 + kof[0]];
            short8 m1_ = *(const short8*)&Kb[rb1 + kof[1]];
            short8 m2_ = *(const short8*)&Kb[rb1 + kof[2]];
            short8 m3_ = *(const short8*)&Kb[rb1 + kof[3]];
            sc1 = MFMA32(m0_, qf[0], sc1);
            sc1 = MFMA32(m1_, qf[1], sc1);
            sc1 = MFMA32(m2_, qf[2], sc1);
            sc1 = MFMA32(m3_, qf[3], sc1);
        }

        // ---- P = exp2(s), 4-way partial l accumulation ----
        #pragma unroll
        for (int i = 0; i < 16; i += 4) {
            float p0 = __ocml_native_exp2_f32(sc0[i + 0]);
            float p1 = __ocml_native_exp2_f32(sc0[i + 1]);
            float p2 = __ocml_native_exp2_f32(sc0[i + 2]);
            float p3 = __ocml_native_exp2_f32(sc0[i + 3]);
            sc0[i + 0] = p0; sc0[i + 1] = p1; sc0[i + 2] = p2; sc0[i + 3] = p3;
            ls0 += p0; ls1 += p1; ls2 += p2; ls3 += p3;
        }
        #pragma unroll
        for (int i = 0; i < 16; i += 4) {
            float p0 = __ocml_native_exp2_f32(sc1[i + 0]);
            float p1 = __ocml_native_exp2_f32(sc1[i + 1]);
            float p2 = __ocml_native_exp2_f32(sc1[i + 2]);
            float p3 = __ocml_native_exp2_f32(sc1[i + 3]);
            sc1[i + 0] = p0; sc1[i + 1] = p1; sc1[i + 2] = p2; sc1[i + 3] = p3;
            ls0 += p0; ls1 += p1; ls2 += p2; ls3 += p3;
        }

        // ---- PV: 4 kv16-steps; P in register order (pi pre-permuted) ----
#define PVSTEP(S, TAU, B8) { \
        union { unsigned u[4]; short8 sv; } pb; \
        pb.u[0] = pkbf(S[B8 + 0], S[B8 + 1]); \
        pb.u[1] = pkbf(S[B8 + 2], S[B8 + 3]); \
        pb.u[2] = pkbf(S[B8 + 4], S[B8 + 5]); \
        pb.u[3] = pkbf(S[B8 + 6], S[B8 + 7]); \
        short8 vf0 = *(const short8*)&Vb[rb0 + (TAU) * 16 + vof[0] - (0 ^ sw0) + ((((TAU) * 16 + h5 * 8) ^ sw0) - ((TAU) * 16 + h5 * 8))]; \
        short8 vf1 = *(const short8*)&Vb[rb1 + (((TAU) * 16 + h5 * 8) ^ sw0)]; \
        o0 = MFMA32(vf0, pb.sv, o0); \
        o1 = MFMA32(vf1, pb.sv, o1); }
        // (vf0 expression simplified below — use direct form)
#undef PVSTEP
#define PVSTEP(S, TAU, B8) { \
        union { unsigned u[4]; short8 sv; } pb; \
        pb.u[0] = pkbf(S[B8 + 0], S[B8 + 1]); \
        pb.u[1] = pkbf(S[B8 + 2], S[B8 + 3]); \
        pb.u[2] = pkbf(S[B8 + 4], S[B8 + 5]); \
        pb.u[3] = pkbf(S[B8 + 6], S[B8 + 7]); \
        const int vcs = (((TAU) * 16 + h5 * 8) ^ sw0); \
        short8 vf0 = *(const short8*)&Vb[rb0 + vcs]; \
        short8 vf1 = *(const short8*)&Vb[rb1 + vcs]; \
        o0 = MFMA32(vf0, pb.sv, o0); \
        o1 = MFMA32(vf1, pb.sv, o1); }

        PVSTEP(sc0, 0, 0);
        PVSTEP(sc0, 1, 8);
        PVSTEP(sc1, 2, 0);
        PVSTEP(sc1, 3, 8);
#undef PVSTEP

        if (tile < 15) __syncthreads();
    }

    // ---- epilogue: O /= l; two-pass transpose through KV scratch ----
    float l_run = (ls0 + ls1) + (ls2 + ls3);
    float l_tot = l_run + __shfl_xor(l_run, 32);
    float inv = 1.0f / l_tot;

    __syncthreads();                 // all tiles consumed; KV reusable
    u16* Ot = &KV[0][0];
    const int bb = bh >> 4, hh = bh & 15;
    const int obase = w * 1280;      // 32 rows x 40 u16 per wave

    #pragma unroll
    for (int pass = 0; pass < 2; ++pass) {
        #pragma unroll
        for (int r = 0; r < 16; r += 2) {
            int dl = (r & 3) + 8 * (r >> 2) + 4 * h5;   // even, 0..31
            float a = (pass ? o1[r]     : o0[r])     * inv;
            float b = (pass ? o1[r + 1] : o0[r + 1]) * inv;
            *(unsigned*)&Ot[obase + ql * 40 + dl] = pkbf(a, b);
        }
        __syncthreads();
        #pragma unroll
        for (int i = 0; i < 2; ++i) {
            int dl = h5 * 16 + i * 8;
            short8 vv = *(const short8*)&Ot[obase + ql * 40 + dl];
            int d = pass * 32 + dl;
            *(short8*)&heads[((size_t)(bb * SEQ + q0 + ql) * NH + hh) * HD + d] = vv;
        }
        __syncthreads();
    }
#undef STAGE
}

// ---------------------------------------------------------------------------
extern "C" void kernel_launch(void* const* d_in, const int* in_sizes, int n_in,
                              void* d_out, int out_size, void* d_ws, size_t ws_size,
                              hipStream_t stream) {
    const float* q  = (const float*)d_in[0];
    const float* x  = (const float*)d_in[1];
    const float* Wq = (const float*)d_in[2];
    const float* bq = (const float*)d_in[3];
    const float* Wk = (const float*)d_in[4];
    const float* bk = (const float*)d_in[5];
    const float* Wv = (const float*)d_in[6];
    const float* bv = (const float*)d_in[7];
    const float* Wp = (const float*)d_in[8];
    const float* bp = (const float*)d_in[9];
    float* out = (float*)d_out;

    const size_t SZ = (size_t)MROWS * DIMS;
    const size_t WZ = (size_t)DIMS * DIMS;
    u16* qb  = (u16*)d_ws;
    u16* xb  = qb  + SZ;
    u16* Wqt = xb  + SZ;
    u16* Wkt = Wqt + WZ;
    u16* Wvt = Wkt + WZ;
    u16* Wpt = Wvt + WZ;
    u16* Qm  = Wpt + WZ;
    u16* Km  = Qm  + SZ;
    u16* Vm  = Km  + SZ;
    u16* Hm  = Vm  + SZ;

    dim3 blk(256);
    const int n8 = (int)(SZ / 8);

    hipLaunchKernelGGL(convert_bf16, dim3(n8 / 256), blk, 0, stream, q, qb, n8);
    hipLaunchKernelGGL(convert_bf16, dim3(n8 / 256), blk, 0, stream, x, xb, n8);
    hipLaunchKernelGGL(transpose_convert, dim3(256), blk, 0, stream, Wq, Wqt);
    hipLaunchKernelGGL(transpose_convert, dim3(256), blk, 0, stream, Wk, Wkt);
    hipLaunchKernelGGL(transpose_convert, dim3(256), blk, 0, stream, Wv, Wvt);
    hipLaunchKernelGGL(transpose_convert, dim3(256), blk, 0, stream, Wp, Wpt);

    dim3 gemm_grid(512);
    const float qscale = 0.125f * 1.4426950408889634f;   // log2 domain
    hipLaunchKernelGGL((gemm_bf16<1>), gemm_grid, blk, 0, stream, qb, Wqt, bq, (void*)Qm, qscale);
    hipLaunchKernelGGL((gemm_bf16<1>), gemm_grid, blk, 0, stream, xb, Wkt, bk, (void*)Km, 1.0f);
    hipLaunchKernelGGL((gemm_bf16<2>), gemm_grid, blk, 0, stream, xb, Wvt, bv, (void*)Vm, 1.0f);

    dim3 attn_grid(NB * NH * (SEQ / 256));  // 512 blocks, 512 threads
    hipLaunchKernelGGL(attn_mfma32_kernel, attn_grid, dim3(512), 0, stream, Qm, Km, Vm, Hm);

    hipLaunchKernelGGL((gemm_bf16<0>), gemm_grid, blk, 0, stream, Hm, Wpt, bp, (void*)out, 1.0f);
}

// Round 10
// 200.221 us; speedup vs baseline: 1.6716x; 1.0411x over previous
//
#include <hip/hip_runtime.h>
#include <hip/hip_bf16.h>
#include <math.h>

#define NB   8
#define SEQ  1024
#define DIMS 1024
#define NH   16
#define HD   64
#define MROWS (NB*SEQ)   // 8192

typedef unsigned short u16;
typedef short short8 __attribute__((ext_vector_type(8)));
typedef short short4v __attribute__((ext_vector_type(4)));
typedef float f32x4 __attribute__((ext_vector_type(4)));
typedef float f32x16 __attribute__((ext_vector_type(16)));

extern "C" __device__ float __ocml_native_exp2_f32(float);   // bare v_exp_f32

__device__ inline u16 f2bf(float f) {
    unsigned u = __float_as_uint(f);
    u += 0x7fff + ((u >> 16) & 1);   // RNE
    return (u16)(u >> 16);
}

__device__ inline unsigned pkbf(float a, float b) {
    float2 f2; f2.x = a; f2.y = b;
    __hip_bfloat162 h = __float22bfloat162_rn(f2);
    return *reinterpret_cast<unsigned*>(&h);
}

#define MFMA16(a, b, c) __builtin_amdgcn_mfma_f32_16x16x32_bf16((a), (b), (c), 0, 0, 0)
#define MFMA32(a, b, c) __builtin_amdgcn_mfma_f32_32x32x16_bf16((a), (b), (c), 0, 0, 0)
#define GLD16(g, l) __builtin_amdgcn_global_load_lds( \
    (const __attribute__((address_space(1))) void*)(g), \
    (__attribute__((address_space(3))) void*)(l), 16, 0, 0)

// ---------------------------------------------------------------------------
// fp32 -> bf16 elementwise (8 elems/thread)
// ---------------------------------------------------------------------------
__global__ __launch_bounds__(256)
void convert_bf16(const float* __restrict__ in, u16* __restrict__ out, int n8)
{
    int i = blockIdx.x * 256 + threadIdx.x;
    if (i >= n8) return;
    float4 v0 = ((const float4*)in)[2 * i];
    float4 v1 = ((const float4*)in)[2 * i + 1];
    union { short8 s; u16 u[8]; } r;
    r.u[0] = f2bf(v0.x); r.u[1] = f2bf(v0.y); r.u[2] = f2bf(v0.z); r.u[3] = f2bf(v0.w);
    r.u[4] = f2bf(v1.x); r.u[5] = f2bf(v1.y); r.u[6] = f2bf(v1.z); r.u[7] = f2bf(v1.w);
    ((short8*)out)[i] = r.s;
}

// ---------------------------------------------------------------------------
// W[k][n] fp32 -> Wt[n][k] bf16 (64x64 tiles, grid 256)
// ---------------------------------------------------------------------------
__global__ __launch_bounds__(256)
void transpose_convert(const float* __restrict__ W, u16* __restrict__ Wt)
{
    __shared__ u16 T[64][72];
    const int t  = threadIdx.x;
    const int k0 = (blockIdx.x >> 4) * 64;
    const int n0 = (blockIdx.x & 15) * 64;
    #pragma unroll
    for (int it = 0; it < 4; ++it) {
        int f  = t + it * 256;
        int kl = f >> 4;
        int n4 = (f & 15) * 4;
        float4 v = *(const float4*)&W[(size_t)(k0 + kl) * DIMS + n0 + n4];
        T[n4 + 0][kl] = f2bf(v.x);
        T[n4 + 1][kl] = f2bf(v.y);
        T[n4 + 2][kl] = f2bf(v.z);
        T[n4 + 3][kl] = f2bf(v.w);
    }
    __syncthreads();
    #pragma unroll
    for (int it = 0; it < 2; ++it) {
        int c  = t + it * 256;
        int nl = c >> 3;
        int k8 = (c & 7) * 8;
        *(short8*)&Wt[(size_t)(n0 + nl) * DIMS + k0 + k8] = *(const short8*)&T[nl][k8];
    }
}

// ---------------------------------------------------------------------------
// bf16 MFMA GEMM: C = A @ Bt^T + bias.  A:[m][k] bf16, Bt:[n][k] bf16.
// 128x128 tile, BK=64, 4 waves, global_load_lds staging.
// T1 XCD swizzle: bn innermost per XCD chunk -> one XCD owns 8 bm x all bn
// (A working set 2MB + B 2MB = one 4MB L2; kills cross-XCD A-panel re-fetch).
// MODE 0: fp32 row-major; MODE 1: bf16 (acc+bias)*scale scatter [b][h][p][d];
// MODE 2: bf16 scatter-transpose [b][h][d][p] with kv-pi-permutation
// ---------------------------------------------------------------------------
template<int MODE>
__global__ __launch_bounds__(256)
void gemm_bf16(const u16* __restrict__ A, const u16* __restrict__ Bt,
               const float* __restrict__ bias, void* __restrict__ Cout, float scale)
{
    __shared__ u16 sm[17408];
    u16* As = sm;
    u16* Bs = sm + 8192;

    const int t    = threadIdx.x;
    const int w    = t >> 6, lane = t & 63;
    const int lo   = lane & 15, hi = lane >> 4;
    // T1: bijective XCD-aware swizzle (nwg=512, 8 XCDs, 64 ids/XCD)
    const int wg   = blockIdx.x;
    const int swzb = (wg & 7) * 64 + (wg >> 3);
    const int bn   = swzb & 7;
    const int bm   = swzb >> 3;
    const int m0   = bm * 128, n0 = bn * 128;
    const int wm   = (w >> 1) * 64, wn = (w & 1) * 64;

    f32x4 acc[4][4];
    #pragma unroll
    for (int mf = 0; mf < 4; ++mf)
        #pragma unroll
        for (int nf = 0; nf < 4; ++nf) acc[mf][nf] = (f32x4){0.f, 0.f, 0.f, 0.f};

    const u16* ga[4]; const u16* gb[4]; u16* la[4]; u16* lb[4];
    #pragma unroll
    for (int i = 0; i < 4; ++i) {
        int c   = (w * 4 + i) * 64 + lane;
        int row = c >> 3, kc = c & 7;
        ga[i] = A  + (size_t)(m0 + row) * 1024 + kc * 8;
        gb[i] = Bt + (size_t)(n0 + row) * 1024 + kc * 8;
        la[i] = As + (w * 4 + i) * 512;
        lb[i] = Bs + (w * 4 + i) * 512;
    }

    for (int kt = 0; kt < 16; ++kt) {
        if (kt) __syncthreads();
        #pragma unroll
        for (int i = 0; i < 4; ++i) {
            GLD16(ga[i] + kt * 64, la[i]);
            GLD16(gb[i] + kt * 64, lb[i]);
        }
        __syncthreads();

        #pragma unroll
        for (int s = 0; s < 2; ++s) {
            short8 fa[4], fb[4];
            #pragma unroll
            for (int mf = 0; mf < 4; ++mf)
                fa[mf] = *(const short8*)&As[(wm + mf * 16 + lo) * 64 + s * 32 + hi * 8];
            #pragma unroll
            for (int nf = 0; nf < 4; ++nf)
                fb[nf] = *(const short8*)&Bs[(wn + nf * 16 + lo) * 64 + s * 32 + hi * 8];
            #pragma unroll
            for (int mf = 0; mf < 4; ++mf)
                #pragma unroll
                for (int nf = 0; nf < 4; ++nf)
                    acc[mf][nf] = MFMA16(fa[mf], fb[nf], acc[mf][nf]);
        }
    }

    if (MODE == 0) {
        float* out = (float*)Cout;
        #pragma unroll
        for (int mf = 0; mf < 4; ++mf)
            #pragma unroll
            for (int j = 0; j < 4; ++j) {
                int r = m0 + wm + mf * 16 + hi * 4 + j;
                #pragma unroll
                for (int nf = 0; nf < 4; ++nf) {
                    int cc = n0 + wn + nf * 16 + lo;
                    out[(size_t)r * 1024 + cc] = acc[mf][nf][j] + bias[cc];
                }
            }
        return;
    }

    __syncthreads();
    if (MODE == 1) {
        #pragma unroll
        for (int mf = 0; mf < 4; ++mf)
            #pragma unroll
            for (int j = 0; j < 4; ++j) {
                int pl = wm + mf * 16 + hi * 4 + j;
                #pragma unroll
                for (int nf = 0; nf < 4; ++nf) {
                    int nl = wn + nf * 16 + lo;
                    int h = nl & 15, dl = nl >> 4;
                    float v = (acc[mf][nf][j] + bias[n0 + nl]) * scale;
                    sm[pl * 136 + h * 8 + dl] = f2bf(v);
                }
            }
        __syncthreads();
        u16* out = (u16*)Cout;
        const int bb = m0 >> 10, p0 = m0 & 1023, dg = n0 >> 4;
        #pragma unroll
        for (int it = 0; it < 8; ++it) {
            int c = t + it * 256;
            int h = c & 15, pl = c >> 4;
            u16* dst = out + ((size_t)((bb * NH + h) * SEQ + p0 + pl)) * HD + dg;
            *(short8*)dst = *(const short8*)&sm[pl * 136 + h * 8];
        }
    } else {
        #pragma unroll
        for (int mf = 0; mf < 4; ++mf)
            #pragma unroll
            for (int j = 0; j < 4; ++j) {
                int pl = wm + mf * 16 + hi * 4 + j;
                #pragma unroll
                for (int nf = 0; nf < 4; ++nf) {
                    int nl = wn + nf * 16 + lo;
                    sm[nl * 136 + pl] = f2bf(acc[mf][nf][j] + bias[n0 + nl]);
                }
            }
        __syncthreads();
        u16* out = (u16*)Cout;
        const int bb = m0 >> 10, p0 = m0 & 1023;
        #pragma unroll
        for (int it = 0; it < 8; ++it) {
            int c  = t + it * 256;
            int nl = c >> 4, p8 = c & 15;
            int ng = n0 + nl;
            int h = ng & 15, d = ng >> 4;
            u16* dstrow = out + ((size_t)((bb * NH + h) * HD + d)) * SEQ + p0;
            const u16* src = &sm[nl * 136 + p8 * 8];
            // pi-permute: 4-elem group g in 16-block -> slot ((g&1)<<1)|(g>>1)
            int base16 = (p8 >> 1) * 16, c8 = p8 & 1;
            *(short4v*)&dstrow[base16 + c8 * 4]     = *(const short4v*)&src[0];
            *(short4v*)&dstrow[base16 + c8 * 4 + 8] = *(const short4v*)&src[4];
        }
    }
}

// ---------------------------------------------------------------------------
// LDS-staged swapped-operand 32x32x16 MFMA flash attention.
// Block = 512 thr / 8 waves = one (b,h) x 256 q-rows; wave owns 32 q.
// K/V double-buffered via global_load_lds; XOR-swizzled LDS (T2);
// unshifted softmax P = exp2(s_log2); pi-permuted PV (register-order pack).
// T5: setprio(1) around MFMA clusters.
// ---------------------------------------------------------------------------
__global__ __launch_bounds__(512, 4)
void attn_mfma32_kernel(const u16* __restrict__ Qm, const u16* __restrict__ Km,
                        const u16* __restrict__ Vp, u16* __restrict__ heads)
{
    __shared__ u16 KV[2][8192];   // [buf][ K:0..4095 | V:4096..8191 ]  32KB

    const int t  = threadIdx.x;          // 0..511
    const int w  = t >> 6, lane = t & 63;
    const int ql = lane & 31, h5 = lane >> 5;

    // XCD-aware bijective swizzle (nwg=512, 8 XCDs), qb innermost
    const int wg  = blockIdx.x;
    const int swz = (wg & 7) * 64 + (wg >> 3);
    const int qb  = swz & 3;
    const int bh  = swz >> 2;
    const int q0  = qb * 256 + w * 32;
    const size_t kbase = (size_t)bh * (SEQ * HD);
    const size_t vbase = (size_t)bh * (HD * SEQ);

    // staging: thread t owns 16B chunk t; global source is inverse-swizzled
    const int lc = t ^ ((t >> 3) & 7);
    const u16* gK = Km + kbase + (size_t)lc * 8;                        // tile-contig
    const u16* gV = Vp + vbase + (size_t)(t >> 3) * SEQ + (lc & 7) * 8; // row stride SEQ
    const int ldK = w * 512;          // wave-uniform LDS dest (u16 idx)
    const int ldV = 4096 + w * 512;

#define STAGE(B, T) do { \
    GLD16(gK + (size_t)(T) * 4096, &KV[B][ldK]); \
    GLD16(gV + (T) * 64,           &KV[B][ldV]); } while (0)

    STAGE(0, 0);

    // Q B-fragments: lane holds Q[q0+ql][d = td*16 + h5*8 + 0..7]
    short8 qf[4];
    #pragma unroll
    for (int td = 0; td < 4; ++td)
        qf[td] = *(const short8*)&Qm[kbase + (size_t)(q0 + ql) * HD + td * 16 + h5 * 8];

    // loop-invariant swizzled LDS offsets (u16 units)
    const int sw0 = (ql & 7) << 3;
    const int rb0 = ql * 64, rb1 = (32 + ql) * 64;
    int kof[4];
    #pragma unroll
    for (int i = 0; i < 4; ++i)
        kof[i] = (i * 16 + h5 * 8) ^ sw0;

    f32x16 o0, o1;
    #pragma unroll
    for (int i = 0; i < 16; ++i) { o0[i] = 0.f; o1[i] = 0.f; }
    float ls0 = 0.f, ls1 = 0.f, ls2 = 0.f, ls3 = 0.f;

    __syncthreads();   // tile 0 staged (implicit vmcnt drain)

    for (int tile = 0; tile < 16; ++tile) {
        const int buf = tile & 1;
        if (tile < 15) STAGE(buf ^ 1, tile + 1);

        const u16* Kb = &KV[buf][0];
        const u16* Vb = &KV[buf][4096];

        // ---- QK: two 32x32 score tiles (log2 domain) ----
        f32x16 sc0, sc1;
        #pragma unroll
        for (int i = 0; i < 16; ++i) { sc0[i] = 0.f; sc1[i] = 0.f; }
        {
            short8 k0 = *(const short8*)&Kb[rb0 + kof[0]];
            short8 k1 = *(const short8*)&Kb[rb0 + kof[1]];
            short8 k2 = *(const short8*)&Kb[rb0 + kof[2]];
            short8 k3 = *(const short8*)&Kb[rb0 + kof[3]];
            short8 m0_ = *(const short8*)&Kb[rb1 + kof[0]];
            short8 m1_ = *(const short8*)&Kb[rb1 + kof[1]];
            short8 m2_ = *(const short8*)&Kb[rb1 + kof[2]];
            short8 m3_ = *(const short8*)&Kb[rb1 + kof[3]];
            __builtin_amdgcn_s_setprio(1);
            sc0 = MFMA32(k0, qf[0], sc0);
            sc0 = MFMA32(k1, qf[1], sc0);
            sc0 = MFMA32(k2, qf[2], sc0);
            sc0 = MFMA32(k3, qf[3], sc0);
            sc1 = MFMA32(m0_, qf[0], sc1);
            sc1 = MFMA32(m1_, qf[1], sc1);
            sc1 = MFMA32(m2_, qf[2], sc1);
            sc1 = MFMA32(m3_, qf[3], sc1);
            __builtin_amdgcn_s_setprio(0);
        }

        // ---- P = exp2(s), 4-way partial l accumulation ----
        #pragma unroll
        for (int i = 0; i < 16; i += 4) {
            float p0 = __ocml_native_exp2_f32(sc0[i + 0]);
            float p1 = __ocml_native_exp2_f32(sc0[i + 1]);
            float p2 = __ocml_native_exp2_f32(sc0[i + 2]);
            float p3 = __ocml_native_exp2_f32(sc0[i + 3]);
            sc0[i + 0] = p0; sc0[i + 1] = p1; sc0[i + 2] = p2; sc0[i + 3] = p3;
            ls0 += p0; ls1 += p1; ls2 += p2; ls3 += p3;
        }
        #pragma unroll
        for (int i = 0; i < 16; i += 4) {
            float p0 = __ocml_native_exp2_f32(sc1[i + 0]);
            float p1 = __ocml_native_exp2_f32(sc1[i + 1]);
            float p2 = __ocml_native_exp2_f32(sc1[i + 2]);
            float p3 = __ocml_native_exp2_f32(sc1[i + 3]);
            sc1[i + 0] = p0; sc1[i + 1] = p1; sc1[i + 2] = p2; sc1[i + 3] = p3;
            ls0 += p0; ls1 += p1; ls2 += p2; ls3 += p3;
        }

        // ---- PV: 4 kv16-steps; P in register order (pi pre-permuted) ----
#define PVSTEP(S, TAU, B8) { \
        union { unsigned u[4]; short8 sv; } pb; \
        pb.u[0] = pkbf(S[B8 + 0], S[B8 + 1]); \
        pb.u[1] = pkbf(S[B8 + 2], S[B8 + 3]); \
        pb.u[2] = pkbf(S[B8 + 4], S[B8 + 5]); \
        pb.u[3] = pkbf(S[B8 + 6], S[B8 + 7]); \
        const int vcs = (((TAU) * 16 + h5 * 8) ^ sw0); \
        short8 vf0 = *(const short8*)&Vb[rb0 + vcs]; \
        short8 vf1 = *(const short8*)&Vb[rb1 + vcs]; \
        __builtin_amdgcn_s_setprio(1); \
        o0 = MFMA32(vf0, pb.sv, o0); \
        o1 = MFMA32(vf1, pb.sv, o1); \
        __builtin_amdgcn_s_setprio(0); }

        PVSTEP(sc0, 0, 0);
        PVSTEP(sc0, 1, 8);
        PVSTEP(sc1, 2, 0);
        PVSTEP(sc1, 3, 8);
#undef PVSTEP

        if (tile < 15) __syncthreads();
    }

    // ---- epilogue: O /= l; two-pass transpose through KV scratch ----
    float l_run = (ls0 + ls1) + (ls2 + ls3);
    float l_tot = l_run + __shfl_xor(l_run, 32);
    float inv = 1.0f / l_tot;

    __syncthreads();                 // all tiles consumed; KV reusable
    u16* Ot = &KV[0][0];
    const int bb = bh >> 4, hh = bh & 15;
    const int obase = w * 1280;      // 32 rows x 40 u16 per wave

    #pragma unroll
    for (int pass = 0; pass < 2; ++pass) {
        #pragma unroll
        for (int r = 0; r < 16; r += 2) {
            int dl = (r & 3) + 8 * (r >> 2) + 4 * h5;   // even, 0..31
            float a = (pass ? o1[r]     : o0[r])     * inv;
            float b = (pass ? o1[r + 1] : o0[r + 1]) * inv;
            *(unsigned*)&Ot[obase + ql * 40 + dl] = pkbf(a, b);
        }
        __syncthreads();
        #pragma unroll
        for (int i = 0; i < 2; ++i) {
            int dl = h5 * 16 + i * 8;
            short8 vv = *(const short8*)&Ot[obase + ql * 40 + dl];
            int d = pass * 32 + dl;
            *(short8*)&heads[((size_t)(bb * SEQ + q0 + ql) * NH + hh) * HD + d] = vv;
        }
        __syncthreads();
    }
#undef STAGE
}

// ---------------------------------------------------------------------------
extern "C" void kernel_launch(void* const* d_in, const int* in_sizes, int n_in,
                              void* d_out, int out_size, void* d_ws, size_t ws_size,
                              hipStream_t stream) {
    const float* q  = (const float*)d_in[0];
    const float* x  = (const float*)d_in[1];
    const float* Wq = (const float*)d_in[2];
    const float* bq = (const float*)d_in[3];
    const float* Wk = (const float*)d_in[4];
    const float* bk = (const float*)d_in[5];
    const float* Wv = (const float*)d_in[6];
    const float* bv = (const float*)d_in[7];
    const float* Wp = (const float*)d_in[8];
    const float* bp = (const float*)d_in[9];
    float* out = (float*)d_out;

    const size_t SZ = (size_t)MROWS * DIMS;
    const size_t WZ = (size_t)DIMS * DIMS;
    u16* qb  = (u16*)d_ws;
    u16* xb  = qb  + SZ;
    u16* Wqt = xb  + SZ;
    u16* Wkt = Wqt + WZ;
    u16* Wvt = Wkt + WZ;
    u16* Wpt = Wvt + WZ;
    u16* Qm  = Wpt + WZ;
    u16* Km  = Qm  + SZ;
    u16* Vm  = Km  + SZ;
    u16* Hm  = Vm  + SZ;

    dim3 blk(256);
    const int n8 = (int)(SZ / 8);

    hipLaunchKernelGGL(convert_bf16, dim3(n8 / 256), blk, 0, stream, q, qb, n8);
    hipLaunchKernelGGL(convert_bf16, dim3(n8 / 256), blk, 0, stream, x, xb, n8);
    hipLaunchKernelGGL(transpose_convert, dim3(256), blk, 0, stream, Wq, Wqt);
    hipLaunchKernelGGL(transpose_convert, dim3(256), blk, 0, stream, Wk, Wkt);
    hipLaunchKernelGGL(transpose_convert, dim3(256), blk, 0, stream, Wv, Wvt);
    hipLaunchKernelGGL(transpose_convert, dim3(256), blk, 0, stream, Wp, Wpt);

    dim3 gemm_grid(512);
    const float qscale = 0.125f * 1.4426950408889634f;   // log2 domain
    hipLaunchKernelGGL((gemm_bf16<1>), gemm_grid, blk, 0, stream, qb, Wqt, bq, (void*)Qm, qscale);
    hipLaunchKernelGGL((gemm_bf16<1>), gemm_grid, blk, 0, stream, xb, Wkt, bk, (void*)Km, 1.0f);
    hipLaunchKernelGGL((gemm_bf16<2>), gemm_grid, blk, 0, stream, xb, Wvt, bv, (void*)Vm, 1.0f);

    dim3 attn_grid(NB * NH * (SEQ / 256));  // 512 blocks, 512 threads
    hipLaunchKernelGGL(attn_mfma32_kernel, attn_grid, dim3(512), 0, stream, Qm, Km, Vm, Hm);

    hipLaunchKernelGGL((gemm_bf16<0>), gemm_grid, blk, 0, stream, Hm, Wpt, bp, (void*)out, 1.0f);
}

// Round 11
// 182.838 us; speedup vs baseline: 1.8306x; 1.0951x over previous
//
#include <hip/hip_runtime.h>
#include <hip/hip_bf16.h>
#include <math.h>

#define NB   8
#define SEQ  1024
#define DIMS 1024
#define NH   16
#define HD   64
#define MROWS (NB*SEQ)   // 8192

typedef unsigned short u16;
typedef short short8 __attribute__((ext_vector_type(8)));
typedef short short4v __attribute__((ext_vector_type(4)));
typedef float f32x4 __attribute__((ext_vector_type(4)));
typedef float f32x16 __attribute__((ext_vector_type(16)));

extern "C" __device__ float __ocml_native_exp2_f32(float);   // bare v_exp_f32

__device__ inline u16 f2bf(float f) {
    unsigned u = __float_as_uint(f);
    u += 0x7fff + ((u >> 16) & 1);   // RNE
    return (u16)(u >> 16);
}

__device__ inline unsigned pkbf(float a, float b) {
    float2 f2; f2.x = a; f2.y = b;
    __hip_bfloat162 h = __float22bfloat162_rn(f2);
    return *reinterpret_cast<unsigned*>(&h);
}

#define MFMA16(a, b, c) __builtin_amdgcn_mfma_f32_16x16x32_bf16((a), (b), (c), 0, 0, 0)
#define MFMA32(a, b, c) __builtin_amdgcn_mfma_f32_32x32x16_bf16((a), (b), (c), 0, 0, 0)
#define GLD16(g, l) __builtin_amdgcn_global_load_lds( \
    (const __attribute__((address_space(1))) void*)(g), \
    (__attribute__((address_space(3))) void*)(l), 16, 0, 0)

// ---------------------------------------------------------------------------
// fp32 -> bf16 elementwise, q and x in ONE launch (4096 blocks each)
// ---------------------------------------------------------------------------
__global__ __launch_bounds__(256)
void convert_both(const float* __restrict__ qin, const float* __restrict__ xin,
                  u16* __restrict__ qo, u16* __restrict__ xo)
{
    const int half = (MROWS * DIMS / 8) / 256;         // 4096
    const float* in = (blockIdx.x < half) ? qin : xin;
    u16* out        = (blockIdx.x < half) ? qo  : xo;
    int i = (blockIdx.x < half ? blockIdx.x : blockIdx.x - half) * 256 + threadIdx.x;
    float4 v0 = ((const float4*)in)[2 * i];
    float4 v1 = ((const float4*)in)[2 * i + 1];
    union { short8 s; u16 u[8]; } r;
    r.u[0] = f2bf(v0.x); r.u[1] = f2bf(v0.y); r.u[2] = f2bf(v0.z); r.u[3] = f2bf(v0.w);
    r.u[4] = f2bf(v1.x); r.u[5] = f2bf(v1.y); r.u[6] = f2bf(v1.z); r.u[7] = f2bf(v1.w);
    ((short8*)out)[i] = r.s;
}

// ---------------------------------------------------------------------------
// All four W[k][n] fp32 -> Wt[n][k] bf16 transposes in ONE launch (1024 blks)
// ---------------------------------------------------------------------------
__global__ __launch_bounds__(256)
void transpose_all(const float* __restrict__ W0, const float* __restrict__ W1,
                   const float* __restrict__ W2, const float* __restrict__ W3,
                   u16* __restrict__ T0, u16* __restrict__ T1o,
                   u16* __restrict__ T2, u16* __restrict__ T3)
{
    __shared__ u16 T[64][72];
    const int which = blockIdx.x >> 8;
    const int idx   = blockIdx.x & 255;
    const float* W = which == 0 ? W0 : which == 1 ? W1 : which == 2 ? W2 : W3;
    u16*        Wt = which == 0 ? T0 : which == 1 ? T1o : which == 2 ? T2 : T3;
    const int t  = threadIdx.x;
    const int k0 = (idx >> 4) * 64;
    const int n0 = (idx & 15) * 64;
    #pragma unroll
    for (int it = 0; it < 4; ++it) {
        int f  = t + it * 256;
        int kl = f >> 4;
        int n4 = (f & 15) * 4;
        float4 v = *(const float4*)&W[(size_t)(k0 + kl) * DIMS + n0 + n4];
        T[n4 + 0][kl] = f2bf(v.x);
        T[n4 + 1][kl] = f2bf(v.y);
        T[n4 + 2][kl] = f2bf(v.z);
        T[n4 + 3][kl] = f2bf(v.w);
    }
    __syncthreads();
    #pragma unroll
    for (int it = 0; it < 2; ++it) {
        int c  = t + it * 256;
        int nl = c >> 3;
        int k8 = (c & 7) * 8;
        *(short8*)&Wt[(size_t)(n0 + nl) * DIMS + k0 + k8] = *(const short8*)&T[nl][k8];
    }
}

// ---------------------------------------------------------------------------
// FUSED Q/K/V projection GEMM: 1536 WGs (3 x 512), which = swz/512.
// 128x128 tile, BK=64, 4 waves, global_load_lds staging, T1 XCD swizzle.
// which 0: Qm = (qb@Wq + bq)*qscale  -> [b][h][p][d]
// which 1: Km = xb@Wk + bk           -> [b][h][p][d]
// which 2: Vm = xb@Wv + bv           -> [b][h][d][p], kv-pi-permuted
// ---------------------------------------------------------------------------
__global__ __launch_bounds__(256)
void gemm_qkv(const u16* __restrict__ qb, const u16* __restrict__ xb,
              const u16* __restrict__ Wqt, const u16* __restrict__ Wkt,
              const u16* __restrict__ Wvt,
              const float* __restrict__ bq, const float* __restrict__ bk,
              const float* __restrict__ bv,
              u16* __restrict__ Qm, u16* __restrict__ Km, u16* __restrict__ Vm,
              float qscale)
{
    __shared__ u16 sm[17408];
    u16* As = sm;
    u16* Bs = sm + 8192;

    const int t    = threadIdx.x;
    const int w    = t >> 6, lane = t & 63;
    const int lo   = lane & 15, hi = lane >> 4;
    // T1 bijective swizzle over nwg=1536 (192 ids per XCD), bn innermost
    const int wg   = blockIdx.x;
    const int swzb = (wg & 7) * 192 + (wg >> 3);
    const int which = swzb / 512;
    const int rem   = swzb - which * 512;
    const int bn   = rem & 7;
    const int bm   = rem >> 3;
    const int m0   = bm * 128, n0 = bn * 128;
    const int wm   = (w >> 1) * 64, wn = (w & 1) * 64;

    const u16* A    = which == 0 ? qb  : xb;
    const u16* Bt   = which == 0 ? Wqt : which == 1 ? Wkt : Wvt;
    const float* bias = which == 0 ? bq : which == 1 ? bk : bv;
    const float scale = which == 0 ? qscale : 1.0f;

    f32x4 acc[4][4];
    #pragma unroll
    for (int mf = 0; mf < 4; ++mf)
        #pragma unroll
        for (int nf = 0; nf < 4; ++nf) acc[mf][nf] = (f32x4){0.f, 0.f, 0.f, 0.f};

    const u16* ga[4]; const u16* gb[4]; u16* la[4]; u16* lb[4];
    #pragma unroll
    for (int i = 0; i < 4; ++i) {
        int c   = (w * 4 + i) * 64 + lane;
        int row = c >> 3, kc = c & 7;
        ga[i] = A  + (size_t)(m0 + row) * 1024 + kc * 8;
        gb[i] = Bt + (size_t)(n0 + row) * 1024 + kc * 8;
        la[i] = As + (w * 4 + i) * 512;
        lb[i] = Bs + (w * 4 + i) * 512;
    }

    for (int kt = 0; kt < 16; ++kt) {
        if (kt) __syncthreads();
        #pragma unroll
        for (int i = 0; i < 4; ++i) {
            GLD16(ga[i] + kt * 64, la[i]);
            GLD16(gb[i] + kt * 64, lb[i]);
        }
        __syncthreads();

        #pragma unroll
        for (int s = 0; s < 2; ++s) {
            short8 fa[4], fb[4];
            #pragma unroll
            for (int mf = 0; mf < 4; ++mf)
                fa[mf] = *(const short8*)&As[(wm + mf * 16 + lo) * 64 + s * 32 + hi * 8];
            #pragma unroll
            for (int nf = 0; nf < 4; ++nf)
                fb[nf] = *(const short8*)&Bs[(wn + nf * 16 + lo) * 64 + s * 32 + hi * 8];
            #pragma unroll
            for (int mf = 0; mf < 4; ++mf)
                #pragma unroll
                for (int nf = 0; nf < 4; ++nf)
                    acc[mf][nf] = MFMA16(fa[mf], fb[nf], acc[mf][nf]);
        }
    }

    __syncthreads();
    if (which < 2) {
        u16* out = which == 0 ? Qm : Km;
        #pragma unroll
        for (int mf = 0; mf < 4; ++mf)
            #pragma unroll
            for (int j = 0; j < 4; ++j) {
                int pl = wm + mf * 16 + hi * 4 + j;
                #pragma unroll
                for (int nf = 0; nf < 4; ++nf) {
                    int nl = wn + nf * 16 + lo;
                    int h = nl & 15, dl = nl >> 4;
                    float v = (acc[mf][nf][j] + bias[n0 + nl]) * scale;
                    sm[pl * 136 + h * 8 + dl] = f2bf(v);
                }
            }
        __syncthreads();
        const int bb = m0 >> 10, p0 = m0 & 1023, dg = n0 >> 4;
        #pragma unroll
        for (int it = 0; it < 8; ++it) {
            int c = t + it * 256;
            int h = c & 15, pl = c >> 4;
            u16* dst = out + ((size_t)((bb * NH + h) * SEQ + p0 + pl)) * HD + dg;
            *(short8*)dst = *(const short8*)&sm[pl * 136 + h * 8];
        }
    } else {
        #pragma unroll
        for (int mf = 0; mf < 4; ++mf)
            #pragma unroll
            for (int j = 0; j < 4; ++j) {
                int pl = wm + mf * 16 + hi * 4 + j;
                #pragma unroll
                for (int nf = 0; nf < 4; ++nf) {
                    int nl = wn + nf * 16 + lo;
                    sm[nl * 136 + pl] = f2bf(acc[mf][nf][j] + bias[n0 + nl]);
                }
            }
        __syncthreads();
        const int bb = m0 >> 10, p0 = m0 & 1023;
        #pragma unroll
        for (int it = 0; it < 8; ++it) {
            int c  = t + it * 256;
            int nl = c >> 4, p8 = c & 15;
            int ng = n0 + nl;
            int h = ng & 15, d = ng >> 4;
            u16* dstrow = Vm + ((size_t)((bb * NH + h) * HD + d)) * SEQ + p0;
            const u16* src = &sm[nl * 136 + p8 * 8];
            // pi-permute: 4-elem group g in 16-block -> slot ((g&1)<<1)|(g>>1)
            int base16 = (p8 >> 1) * 16, c8 = p8 & 1;
            *(short4v*)&dstrow[base16 + c8 * 4]     = *(const short4v*)&src[0];
            *(short4v*)&dstrow[base16 + c8 * 4 + 8] = *(const short4v*)&src[4];
        }
    }
}

// ---------------------------------------------------------------------------
// Final projection GEMM: C(fp32) = Hm @ Wpt^T + bp. 128x128, T1 swizzle.
// ---------------------------------------------------------------------------
__global__ __launch_bounds__(256)
void gemm_out(const u16* __restrict__ A, const u16* __restrict__ Bt,
              const float* __restrict__ bias, float* __restrict__ out)
{
    __shared__ u16 sm[16384];
    u16* As = sm;
    u16* Bs = sm + 8192;

    const int t    = threadIdx.x;
    const int w    = t >> 6, lane = t & 63;
    const int lo   = lane & 15, hi = lane >> 4;
    const int wg   = blockIdx.x;
    const int swzb = (wg & 7) * 64 + (wg >> 3);
    const int bn   = swzb & 7;
    const int bm   = swzb >> 3;
    const int m0   = bm * 128, n0 = bn * 128;
    const int wm   = (w >> 1) * 64, wn = (w & 1) * 64;

    f32x4 acc[4][4];
    #pragma unroll
    for (int mf = 0; mf < 4; ++mf)
        #pragma unroll
        for (int nf = 0; nf < 4; ++nf) acc[mf][nf] = (f32x4){0.f, 0.f, 0.f, 0.f};

    const u16* ga[4]; const u16* gb[4]; u16* la[4]; u16* lb[4];
    #pragma unroll
    for (int i = 0; i < 4; ++i) {
        int c   = (w * 4 + i) * 64 + lane;
        int row = c >> 3, kc = c & 7;
        ga[i] = A  + (size_t)(m0 + row) * 1024 + kc * 8;
        gb[i] = Bt + (size_t)(n0 + row) * 1024 + kc * 8;
        la[i] = As + (w * 4 + i) * 512;
        lb[i] = Bs + (w * 4 + i) * 512;
    }

    for (int kt = 0; kt < 16; ++kt) {
        if (kt) __syncthreads();
        #pragma unroll
        for (int i = 0; i < 4; ++i) {
            GLD16(ga[i] + kt * 64, la[i]);
            GLD16(gb[i] + kt * 64, lb[i]);
        }
        __syncthreads();

        #pragma unroll
        for (int s = 0; s < 2; ++s) {
            short8 fa[4], fb[4];
            #pragma unroll
            for (int mf = 0; mf < 4; ++mf)
                fa[mf] = *(const short8*)&As[(wm + mf * 16 + lo) * 64 + s * 32 + hi * 8];
            #pragma unroll
            for (int nf = 0; nf < 4; ++nf)
                fb[nf] = *(const short8*)&Bs[(wn + nf * 16 + lo) * 64 + s * 32 + hi * 8];
            #pragma unroll
            for (int mf = 0; mf < 4; ++mf)
                #pragma unroll
                for (int nf = 0; nf < 4; ++nf)
                    acc[mf][nf] = MFMA16(fa[mf], fb[nf], acc[mf][nf]);
        }
    }

    #pragma unroll
    for (int mf = 0; mf < 4; ++mf)
        #pragma unroll
        for (int j = 0; j < 4; ++j) {
            int r = m0 + wm + mf * 16 + hi * 4 + j;
            #pragma unroll
            for (int nf = 0; nf < 4; ++nf) {
                int cc = n0 + wn + nf * 16 + lo;
                out[(size_t)r * 1024 + cc] = acc[mf][nf][j] + bias[cc];
            }
        }
}

// ---------------------------------------------------------------------------
// LDS-staged swapped-operand 32x32x16 MFMA flash attention (r9 version —
// setprio removed: T5 needs role-split, this loop is barrier-lockstep).
// ---------------------------------------------------------------------------
__global__ __launch_bounds__(512, 4)
void attn_mfma32_kernel(const u16* __restrict__ Qm, const u16* __restrict__ Km,
                        const u16* __restrict__ Vp, u16* __restrict__ heads)
{
    __shared__ u16 KV[2][8192];   // [buf][ K:0..4095 | V:4096..8191 ]  32KB

    const int t  = threadIdx.x;          // 0..511
    const int w  = t >> 6, lane = t & 63;
    const int ql = lane & 31, h5 = lane >> 5;

    const int wg  = blockIdx.x;
    const int swz = (wg & 7) * 64 + (wg >> 3);
    const int qb  = swz & 3;
    const int bh  = swz >> 2;
    const int q0  = qb * 256 + w * 32;
    const size_t kbase = (size_t)bh * (SEQ * HD);
    const size_t vbase = (size_t)bh * (HD * SEQ);

    const int lc = t ^ ((t >> 3) & 7);
    const u16* gK = Km + kbase + (size_t)lc * 8;
    const u16* gV = Vp + vbase + (size_t)(t >> 3) * SEQ + (lc & 7) * 8;
    const int ldK = w * 512;
    const int ldV = 4096 + w * 512;

#define STAGE(B, T) do { \
    GLD16(gK + (size_t)(T) * 4096, &KV[B][ldK]); \
    GLD16(gV + (T) * 64,           &KV[B][ldV]); } while (0)

    STAGE(0, 0);

    short8 qf[4];
    #pragma unroll
    for (int td = 0; td < 4; ++td)
        qf[td] = *(const short8*)&Qm[kbase + (size_t)(q0 + ql) * HD + td * 16 + h5 * 8];

    const int sw0 = (ql & 7) << 3;
    const int rb0 = ql * 64, rb1 = (32 + ql) * 64;
    int kof[4];
    #pragma unroll
    for (int i = 0; i < 4; ++i)
        kof[i] = (i * 16 + h5 * 8) ^ sw0;

    f32x16 o0, o1;
    #pragma unroll
    for (int i = 0; i < 16; ++i) { o0[i] = 0.f; o1[i] = 0.f; }
    float ls0 = 0.f, ls1 = 0.f, ls2 = 0.f, ls3 = 0.f;

    __syncthreads();

    for (int tile = 0; tile < 16; ++tile) {
        const int buf = tile & 1;
        if (tile < 15) STAGE(buf ^ 1, tile + 1);

        const u16* Kb = &KV[buf][0];
        const u16* Vb = &KV[buf][4096];

        f32x16 sc0, sc1;
        #pragma unroll
        for (int i = 0; i < 16; ++i) { sc0[i] = 0.f; sc1[i] = 0.f; }
        {
            short8 k0 = *(const short8*)&Kb[rb0 + kof[0]];
            short8 k1 = *(const short8*)&Kb[rb0 + kof[1]];
            short8 k2 = *(const short8*)&Kb[rb0 + kof[2]];
            short8 k3 = *(const short8*)&Kb[rb0 + kof[3]];
            sc0 = MFMA32(k0, qf[0], sc0);
            sc0 = MFMA32(k1, qf[1], sc0);
            sc0 = MFMA32(k2, qf[2], sc0);
            sc0 = MFMA32(k3, qf[3], sc0);
            short8 m0_ = *(const short8*)&Kb[rb1 + kof[0]];
            short8 m1_ = *(const short8*)&Kb[rb1 + kof[1]];
            short8 m2_ = *(const short8*)&Kb[rb1 + kof[2]];
            short8 m3_ = *(const short8*)&Kb[rb1 + kof[3]];
            sc1 = MFMA32(m0_, qf[0], sc1);
            sc1 = MFMA32(m1_, qf[1], sc1);
            sc1 = MFMA32(m2_, qf[2], sc1);
            sc1 = MFMA32(m3_, qf[3], sc1);
        }

        #pragma unroll
        for (int i = 0; i < 16; i += 4) {
            float p0 = __ocml_native_exp2_f32(sc0[i + 0]);
            float p1 = __ocml_native_exp2_f32(sc0[i + 1]);
            float p2 = __ocml_native_exp2_f32(sc0[i + 2]);
            float p3 = __ocml_native_exp2_f32(sc0[i + 3]);
            sc0[i + 0] = p0; sc0[i + 1] = p1; sc0[i + 2] = p2; sc0[i + 3] = p3;
            ls0 += p0; ls1 += p1; ls2 += p2; ls3 += p3;
        }
        #pragma unroll
        for (int i = 0; i < 16; i += 4) {
            float p0 = __ocml_native_exp2_f32(sc1[i + 0]);
            float p1 = __ocml_native_exp2_f32(sc1[i + 1]);
            float p2 = __ocml_native_exp2_f32(sc1[i + 2]);
            float p3 = __ocml_native_exp2_f32(sc1[i + 3]);
            sc1[i + 0] = p0; sc1[i + 1] = p1; sc1[i + 2] = p2; sc1[i + 3] = p3;
            ls0 += p0; ls1 += p1; ls2 += p2; ls3 += p3;
        }

#define PVSTEP(S, TAU, B8) { \
        union { unsigned u[4]; short8 sv; } pb; \
        pb.u[0] = pkbf(S[B8 + 0], S[B8 + 1]); \
        pb.u[1] = pkbf(S[B8 + 2], S[B8 + 3]); \
        pb.u[2] = pkbf(S[B8 + 4], S[B8 + 5]); \
        pb.u[3] = pkbf(S[B8 + 6], S[B8 + 7]); \
        const int vcs = (((TAU) * 16 + h5 * 8) ^ sw0); \
        short8 vf0 = *(const short8*)&Vb[rb0 + vcs]; \
        short8 vf1 = *(const short8*)&Vb[rb1 + vcs]; \
        o0 = MFMA32(vf0, pb.sv, o0); \
        o1 = MFMA32(vf1, pb.sv, o1); }

        PVSTEP(sc0, 0, 0);
        PVSTEP(sc0, 1, 8);
        PVSTEP(sc1, 2, 0);
        PVSTEP(sc1, 3, 8);
#undef PVSTEP

        if (tile < 15) __syncthreads();
    }

    float l_run = (ls0 + ls1) + (ls2 + ls3);
    float l_tot = l_run + __shfl_xor(l_run, 32);
    float inv = 1.0f / l_tot;

    __syncthreads();
    u16* Ot = &KV[0][0];
    const int bb = bh >> 4, hh = bh & 15;
    const int obase = w * 1280;

    #pragma unroll
    for (int pass = 0; pass < 2; ++pass) {
        #pragma unroll
        for (int r = 0; r < 16; r += 2) {
            int dl = (r & 3) + 8 * (r >> 2) + 4 * h5;
            float a = (pass ? o1[r]     : o0[r])     * inv;
            float b = (pass ? o1[r + 1] : o0[r + 1]) * inv;
            *(unsigned*)&Ot[obase + ql * 40 + dl] = pkbf(a, b);
        }
        __syncthreads();
        #pragma unroll
        for (int i = 0; i < 2; ++i) {
            int dl = h5 * 16 + i * 8;
            short8 vv = *(const short8*)&Ot[obase + ql * 40 + dl];
            int d = pass * 32 + dl;
            *(short8*)&heads[((size_t)(bb * SEQ + q0 + ql) * NH + hh) * HD + d] = vv;
        }
        __syncthreads();
    }
#undef STAGE
}

// ---------------------------------------------------------------------------
extern "C" void kernel_launch(void* const* d_in, const int* in_sizes, int n_in,
                              void* d_out, int out_size, void* d_ws, size_t ws_size,
                              hipStream_t stream) {
    const float* q  = (const float*)d_in[0];
    const float* x  = (const float*)d_in[1];
    const float* Wq = (const float*)d_in[2];
    const float* bq = (const float*)d_in[3];
    const float* Wk = (const float*)d_in[4];
    const float* bk = (const float*)d_in[5];
    const float* Wv = (const float*)d_in[6];
    const float* bv = (const float*)d_in[7];
    const float* Wp = (const float*)d_in[8];
    const float* bp = (const float*)d_in[9];
    float* out = (float*)d_out;

    const size_t SZ = (size_t)MROWS * DIMS;
    const size_t WZ = (size_t)DIMS * DIMS;
    u16* qb  = (u16*)d_ws;
    u16* xb  = qb  + SZ;
    u16* Wqt = xb  + SZ;
    u16* Wkt = Wqt + WZ;
    u16* Wvt = Wkt + WZ;
    u16* Wpt = Wvt + WZ;
    u16* Qm  = Wpt + WZ;
    u16* Km  = Qm  + SZ;
    u16* Vm  = Km  + SZ;
    u16* Hm  = Vm  + SZ;

    const float qscale = 0.125f * 1.4426950408889634f;   // log2 domain

    hipLaunchKernelGGL(convert_both, dim3(8192), dim3(256), 0, stream, q, x, qb, xb);
    hipLaunchKernelGGL(transpose_all, dim3(1024), dim3(256), 0, stream,
                       Wq, Wk, Wv, Wp, Wqt, Wkt, Wvt, Wpt);
    hipLaunchKernelGGL(gemm_qkv, dim3(1536), dim3(256), 0, stream,
                       qb, xb, Wqt, Wkt, Wvt, bq, bk, bv, Qm, Km, Vm, qscale);
    hipLaunchKernelGGL(attn_mfma32_kernel, dim3(512), dim3(512), 0, stream, Qm, Km, Vm, Hm);
    hipLaunchKernelGGL(gemm_out, dim3(512), dim3(256), 0, stream, Hm, Wpt, bp, out);
}

// Round 12
// 171.601 us; speedup vs baseline: 1.9504x; 1.0655x over previous
//
#include <hip/hip_runtime.h>
#include <hip/hip_bf16.h>
#include <math.h>

#define NB   8
#define SEQ  1024
#define DIMS 1024
#define NH   16
#define HD   64
#define MROWS (NB*SEQ)   // 8192

typedef unsigned short u16;
typedef short short8 __attribute__((ext_vector_type(8)));
typedef short short4v __attribute__((ext_vector_type(4)));
typedef float f32x4 __attribute__((ext_vector_type(4)));
typedef float f32x16 __attribute__((ext_vector_type(16)));

extern "C" __device__ float __ocml_native_exp2_f32(float);   // bare v_exp_f32

__device__ inline u16 f2bf(float f) {
    unsigned u = __float_as_uint(f);
    u += 0x7fff + ((u >> 16) & 1);   // RNE
    return (u16)(u >> 16);
}

__device__ inline unsigned pkbf(float a, float b) {
    float2 f2; f2.x = a; f2.y = b;
    __hip_bfloat162 h = __float22bfloat162_rn(f2);
    return *reinterpret_cast<unsigned*>(&h);
}

#define MFMA16(a, b, c) __builtin_amdgcn_mfma_f32_16x16x32_bf16((a), (b), (c), 0, 0, 0)
#define MFMA32(a, b, c) __builtin_amdgcn_mfma_f32_32x32x16_bf16((a), (b), (c), 0, 0, 0)
#define GLD16(g, l) __builtin_amdgcn_global_load_lds( \
    (const __attribute__((address_space(1))) void*)(g), \
    (__attribute__((address_space(3))) void*)(l), 16, 0, 0)

// ---------------------------------------------------------------------------
// fp32 -> bf16 elementwise, q and x in ONE launch
// ---------------------------------------------------------------------------
__global__ __launch_bounds__(256)
void convert_both(const float* __restrict__ qin, const float* __restrict__ xin,
                  u16* __restrict__ qo, u16* __restrict__ xo)
{
    const int half = (MROWS * DIMS / 8) / 256;         // 4096
    const float* in = (blockIdx.x < half) ? qin : xin;
    u16* out        = (blockIdx.x < half) ? qo  : xo;
    int i = (blockIdx.x < half ? blockIdx.x : blockIdx.x - half) * 256 + threadIdx.x;
    float4 v0 = ((const float4*)in)[2 * i];
    float4 v1 = ((const float4*)in)[2 * i + 1];
    union { short8 s; u16 u[8]; } r;
    r.u[0] = f2bf(v0.x); r.u[1] = f2bf(v0.y); r.u[2] = f2bf(v0.z); r.u[3] = f2bf(v0.w);
    r.u[4] = f2bf(v1.x); r.u[5] = f2bf(v1.y); r.u[6] = f2bf(v1.z); r.u[7] = f2bf(v1.w);
    ((short8*)out)[i] = r.s;
}

// ---------------------------------------------------------------------------
// All four W[k][n] fp32 -> Wt[n][k] bf16 transposes in ONE launch
// ---------------------------------------------------------------------------
__global__ __launch_bounds__(256)
void transpose_all(const float* __restrict__ W0, const float* __restrict__ W1,
                   const float* __restrict__ W2, const float* __restrict__ W3,
                   u16* __restrict__ T0, u16* __restrict__ T1o,
                   u16* __restrict__ T2, u16* __restrict__ T3)
{
    __shared__ u16 T[64][72];
    const int which = blockIdx.x >> 8;
    const int idx   = blockIdx.x & 255;
    const float* W = which == 0 ? W0 : which == 1 ? W1 : which == 2 ? W2 : W3;
    u16*        Wt = which == 0 ? T0 : which == 1 ? T1o : which == 2 ? T2 : T3;
    const int t  = threadIdx.x;
    const int k0 = (idx >> 4) * 64;
    const int n0 = (idx & 15) * 64;
    #pragma unroll
    for (int it = 0; it < 4; ++it) {
        int f  = t + it * 256;
        int kl = f >> 4;
        int n4 = (f & 15) * 4;
        float4 v = *(const float4*)&W[(size_t)(k0 + kl) * DIMS + n0 + n4];
        T[n4 + 0][kl] = f2bf(v.x);
        T[n4 + 1][kl] = f2bf(v.y);
        T[n4 + 2][kl] = f2bf(v.z);
        T[n4 + 3][kl] = f2bf(v.w);
    }
    __syncthreads();
    #pragma unroll
    for (int it = 0; it < 2; ++it) {
        int c  = t + it * 256;
        int nl = c >> 3;
        int k8 = (c & 7) * 8;
        *(short8*)&Wt[(size_t)(n0 + nl) * DIMS + k0 + k8] = *(const short8*)&T[nl][k8];
    }
}

// ---------------------------------------------------------------------------
// FUSED Q/K/V projection GEMM, BK=32 DOUBLE-BUFFERED staging (2-phase):
// STAGE(next tile) issued BEFORE compute(current) so the vmcnt(0)-before-
// barrier drain overlaps the MFMA work. 2 x 16KB staging buffers keep LDS at
// 34.8KB -> 4 blocks/CU residency preserved. 128x128 tile, 4 waves, T1 swz.
// which 0: Qm=(qb@Wq+bq)*qscale -> [b][h][p][d]; 1: Km -> same; 2: Vm ->
// [b][h][d][p] kv-pi-permuted.
// ---------------------------------------------------------------------------
__global__ __launch_bounds__(256)
void gemm_qkv(const u16* __restrict__ qb, const u16* __restrict__ xb,
              const u16* __restrict__ Wqt, const u16* __restrict__ Wkt,
              const u16* __restrict__ Wvt,
              const float* __restrict__ bq, const float* __restrict__ bk,
              const float* __restrict__ bv,
              u16* __restrict__ Qm, u16* __restrict__ Km, u16* __restrict__ Vm,
              float qscale)
{
    __shared__ u16 sm[17408];          // staging: [0..8191]=buf0, [8192..16383]=buf1
    u16* buf0 = sm;                    // each buf: A[128][32] | B[128][32]
    u16* buf1 = sm + 8192;

    const int t    = threadIdx.x;
    const int w    = t >> 6, lane = t & 63;
    const int lo   = lane & 15, hi = lane >> 4;
    const int wg   = blockIdx.x;
    const int swzb = (wg & 7) * 192 + (wg >> 3);     // T1: 192 ids/XCD
    const int which = swzb / 512;
    const int rem   = swzb - which * 512;
    const int bn   = rem & 7;
    const int bm   = rem >> 3;
    const int m0   = bm * 128, n0 = bn * 128;
    const int wm   = (w >> 1) * 64, wn = (w & 1) * 64;

    const u16* A      = which == 0 ? qb  : xb;
    const u16* Bt     = which == 0 ? Wqt : which == 1 ? Wkt : Wvt;
    const float* bias = which == 0 ? bq : which == 1 ? bk : bv;
    const float scale = which == 0 ? qscale : 1.0f;

    f32x4 acc[4][4];
    #pragma unroll
    for (int mf = 0; mf < 4; ++mf)
        #pragma unroll
        for (int nf = 0; nf < 4; ++nf) acc[mf][nf] = (f32x4){0.f, 0.f, 0.f, 0.f};

    // staging addresses: chunk c = i*256 + t; row=c>>2, kc=c&3 (BK=32: 4 chunks/row)
    const u16* ga[2]; const u16* gb[2]; int laOff[2], lbOff[2];
    #pragma unroll
    for (int i = 0; i < 2; ++i) {
        int c   = i * 256 + t;
        int row = c >> 2, kc = c & 3;
        ga[i] = A  + (size_t)(m0 + row) * 1024 + kc * 8;
        gb[i] = Bt + (size_t)(n0 + row) * 1024 + kc * 8;
        laOff[i] = (i * 256 + w * 64) * 8;            // wave-uniform, lane auto x16B
        lbOff[i] = 4096 + (i * 256 + w * 64) * 8;
    }

#define STAGE(BUF, KT) do { \
    GLD16(ga[0] + (KT) * 32, (BUF) + laOff[0]); \
    GLD16(ga[1] + (KT) * 32, (BUF) + laOff[1]); \
    GLD16(gb[0] + (KT) * 32, (BUF) + lbOff[0]); \
    GLD16(gb[1] + (KT) * 32, (BUF) + lbOff[1]); } while (0)

#define COMPUTE(BUF) do { \
    short8 fa[4], fb[4]; \
    _Pragma("unroll") \
    for (int mf = 0; mf < 4; ++mf) \
        fa[mf] = *(const short8*)&(BUF)[(wm + mf * 16 + lo) * 32 + hi * 8]; \
    _Pragma("unroll") \
    for (int nf = 0; nf < 4; ++nf) \
        fb[nf] = *(const short8*)&(BUF)[4096 + (wn + nf * 16 + lo) * 32 + hi * 8]; \
    _Pragma("unroll") \
    for (int mf = 0; mf < 4; ++mf) \
        _Pragma("unroll") \
        for (int nf = 0; nf < 4; ++nf) \
            acc[mf][nf] = MFMA16(fa[mf], fb[nf], acc[mf][nf]); } while (0)

    STAGE(buf0, 0);
    __syncthreads();
    for (int kt = 0; kt < 32; kt += 2) {
        STAGE(buf1, kt + 1);          // kt+1 <= 31 always
        COMPUTE(buf0);
        __syncthreads();
        if (kt + 2 < 32) STAGE(buf0, kt + 2);
        COMPUTE(buf1);
        __syncthreads();
    }
#undef STAGE
#undef COMPUTE

    // ---- epilogue (staging LDS reused as 128x136 scratch) ----
    if (which < 2) {
        u16* out = which == 0 ? Qm : Km;
        #pragma unroll
        for (int mf = 0; mf < 4; ++mf)
            #pragma unroll
            for (int j = 0; j < 4; ++j) {
                int pl = wm + mf * 16 + hi * 4 + j;
                #pragma unroll
                for (int nf = 0; nf < 4; ++nf) {
                    int nl = wn + nf * 16 + lo;
                    int h = nl & 15, dl = nl >> 4;
                    float v = (acc[mf][nf][j] + bias[n0 + nl]) * scale;
                    sm[pl * 136 + h * 8 + dl] = f2bf(v);
                }
            }
        __syncthreads();
        const int bb = m0 >> 10, p0 = m0 & 1023, dg = n0 >> 4;
        #pragma unroll
        for (int it = 0; it < 8; ++it) {
            int c = t + it * 256;
            int h = c & 15, pl = c >> 4;
            u16* dst = out + ((size_t)((bb * NH + h) * SEQ + p0 + pl)) * HD + dg;
            *(short8*)dst = *(const short8*)&sm[pl * 136 + h * 8];
        }
    } else {
        #pragma unroll
        for (int mf = 0; mf < 4; ++mf)
            #pragma unroll
            for (int j = 0; j < 4; ++j) {
                int pl = wm + mf * 16 + hi * 4 + j;
                #pragma unroll
                for (int nf = 0; nf < 4; ++nf) {
                    int nl = wn + nf * 16 + lo;
                    sm[nl * 136 + pl] = f2bf(acc[mf][nf][j] + bias[n0 + nl]);
                }
            }
        __syncthreads();
        const int bb = m0 >> 10, p0 = m0 & 1023;
        #pragma unroll
        for (int it = 0; it < 8; ++it) {
            int c  = t + it * 256;
            int nl = c >> 4, p8 = c & 15;
            int ng = n0 + nl;
            int h = ng & 15, d = ng >> 4;
            u16* dstrow = Vm + ((size_t)((bb * NH + h) * HD + d)) * SEQ + p0;
            const u16* src = &sm[nl * 136 + p8 * 8];
            int base16 = (p8 >> 1) * 16, c8 = p8 & 1;
            *(short4v*)&dstrow[base16 + c8 * 4]     = *(const short4v*)&src[0];
            *(short4v*)&dstrow[base16 + c8 * 4 + 8] = *(const short4v*)&src[4];
        }
    }
}

// ---------------------------------------------------------------------------
// Final projection GEMM, same BK=32 double-buffered structure, fp32 output.
// ---------------------------------------------------------------------------
__global__ __launch_bounds__(256)
void gemm_out(const u16* __restrict__ A, const u16* __restrict__ Bt,
              const float* __restrict__ bias, float* __restrict__ out)
{
    __shared__ u16 sm[16384];
    u16* buf0 = sm;
    u16* buf1 = sm + 8192;

    const int t    = threadIdx.x;
    const int w    = t >> 6, lane = t & 63;
    const int lo   = lane & 15, hi = lane >> 4;
    const int wg   = blockIdx.x;
    const int swzb = (wg & 7) * 64 + (wg >> 3);
    const int bn   = swzb & 7;
    const int bm   = swzb >> 3;
    const int m0   = bm * 128, n0 = bn * 128;
    const int wm   = (w >> 1) * 64, wn = (w & 1) * 64;

    f32x4 acc[4][4];
    #pragma unroll
    for (int mf = 0; mf < 4; ++mf)
        #pragma unroll
        for (int nf = 0; nf < 4; ++nf) acc[mf][nf] = (f32x4){0.f, 0.f, 0.f, 0.f};

    const u16* ga[2]; const u16* gb[2]; int laOff[2], lbOff[2];
    #pragma unroll
    for (int i = 0; i < 2; ++i) {
        int c   = i * 256 + t;
        int row = c >> 2, kc = c & 3;
        ga[i] = A  + (size_t)(m0 + row) * 1024 + kc * 8;
        gb[i] = Bt + (size_t)(n0 + row) * 1024 + kc * 8;
        laOff[i] = (i * 256 + w * 64) * 8;
        lbOff[i] = 4096 + (i * 256 + w * 64) * 8;
    }

#define STAGE(BUF, KT) do { \
    GLD16(ga[0] + (KT) * 32, (BUF) + laOff[0]); \
    GLD16(ga[1] + (KT) * 32, (BUF) + laOff[1]); \
    GLD16(gb[0] + (KT) * 32, (BUF) + lbOff[0]); \
    GLD16(gb[1] + (KT) * 32, (BUF) + lbOff[1]); } while (0)

#define COMPUTE(BUF) do { \
    short8 fa[4], fb[4]; \
    _Pragma("unroll") \
    for (int mf = 0; mf < 4; ++mf) \
        fa[mf] = *(const short8*)&(BUF)[(wm + mf * 16 + lo) * 32 + hi * 8]; \
    _Pragma("unroll") \
    for (int nf = 0; nf < 4; ++nf) \
        fb[nf] = *(const short8*)&(BUF)[4096 + (wn + nf * 16 + lo) * 32 + hi * 8]; \
    _Pragma("unroll") \
    for (int mf = 0; mf < 4; ++mf) \
        _Pragma("unroll") \
        for (int nf = 0; nf < 4; ++nf) \
            acc[mf][nf] = MFMA16(fa[mf], fb[nf], acc[mf][nf]); } while (0)

    STAGE(buf0, 0);
    __syncthreads();
    for (int kt = 0; kt < 32; kt += 2) {
        STAGE(buf1, kt + 1);
        COMPUTE(buf0);
        __syncthreads();
        if (kt + 2 < 32) STAGE(buf0, kt + 2);
        COMPUTE(buf1);
        __syncthreads();
    }
#undef STAGE
#undef COMPUTE

    #pragma unroll
    for (int mf = 0; mf < 4; ++mf)
        #pragma unroll
        for (int j = 0; j < 4; ++j) {
            int r = m0 + wm + mf * 16 + hi * 4 + j;
            #pragma unroll
            for (int nf = 0; nf < 4; ++nf) {
                int cc = n0 + wn + nf * 16 + lo;
                out[(size_t)r * 1024 + cc] = acc[mf][nf][j] + bias[cc];
            }
        }
}

// ---------------------------------------------------------------------------
// LDS-staged swapped-operand 32x32x16 MFMA flash attention (r9/r11 version).
// ---------------------------------------------------------------------------
__global__ __launch_bounds__(512, 4)
void attn_mfma32_kernel(const u16* __restrict__ Qm, const u16* __restrict__ Km,
                        const u16* __restrict__ Vp, u16* __restrict__ heads)
{
    __shared__ u16 KV[2][8192];   // [buf][ K:0..4095 | V:4096..8191 ]  32KB

    const int t  = threadIdx.x;          // 0..511
    const int w  = t >> 6, lane = t & 63;
    const int ql = lane & 31, h5 = lane >> 5;

    const int wg  = blockIdx.x;
    const int swz = (wg & 7) * 64 + (wg >> 3);
    const int qb  = swz & 3;
    const int bh  = swz >> 2;
    const int q0  = qb * 256 + w * 32;
    const size_t kbase = (size_t)bh * (SEQ * HD);
    const size_t vbase = (size_t)bh * (HD * SEQ);

    const int lc = t ^ ((t >> 3) & 7);
    const u16* gK = Km + kbase + (size_t)lc * 8;
    const u16* gV = Vp + vbase + (size_t)(t >> 3) * SEQ + (lc & 7) * 8;
    const int ldK = w * 512;
    const int ldV = 4096 + w * 512;

#define STAGE(B, T) do { \
    GLD16(gK + (size_t)(T) * 4096, &KV[B][ldK]); \
    GLD16(gV + (T) * 64,           &KV[B][ldV]); } while (0)

    STAGE(0, 0);

    short8 qf[4];
    #pragma unroll
    for (int td = 0; td < 4; ++td)
        qf[td] = *(const short8*)&Qm[kbase + (size_t)(q0 + ql) * HD + td * 16 + h5 * 8];

    const int sw0 = (ql & 7) << 3;
    const int rb0 = ql * 64, rb1 = (32 + ql) * 64;
    int kof[4];
    #pragma unroll
    for (int i = 0; i < 4; ++i)
        kof[i] = (i * 16 + h5 * 8) ^ sw0;

    f32x16 o0, o1;
    #pragma unroll
    for (int i = 0; i < 16; ++i) { o0[i] = 0.f; o1[i] = 0.f; }
    float ls0 = 0.f, ls1 = 0.f, ls2 = 0.f, ls3 = 0.f;

    __syncthreads();

    for (int tile = 0; tile < 16; ++tile) {
        const int buf = tile & 1;
        if (tile < 15) STAGE(buf ^ 1, tile + 1);

        const u16* Kb = &KV[buf][0];
        const u16* Vb = &KV[buf][4096];

        f32x16 sc0, sc1;
        #pragma unroll
        for (int i = 0; i < 16; ++i) { sc0[i] = 0.f; sc1[i] = 0.f; }
        {
            short8 k0 = *(const short8*)&Kb[rb0 + kof[0]];
            short8 k1 = *(const short8*)&Kb[rb0 + kof[1]];
            short8 k2 = *(const short8*)&Kb[rb0 + kof[2]];
            short8 k3 = *(const short8*)&Kb[rb0 + kof[3]];
            sc0 = MFMA32(k0, qf[0], sc0);
            sc0 = MFMA32(k1, qf[1], sc0);
            sc0 = MFMA32(k2, qf[2], sc0);
            sc0 = MFMA32(k3, qf[3], sc0);
            short8 m0_ = *(const short8*)&Kb[rb1 + kof[0]];
            short8 m1_ = *(const short8*)&Kb[rb1 + kof[1]];
            short8 m2_ = *(const short8*)&Kb[rb1 + kof[2]];
            short8 m3_ = *(const short8*)&Kb[rb1 + kof[3]];
            sc1 = MFMA32(m0_, qf[0], sc1);
            sc1 = MFMA32(m1_, qf[1], sc1);
            sc1 = MFMA32(m2_, qf[2], sc1);
            sc1 = MFMA32(m3_, qf[3], sc1);
        }

        #pragma unroll
        for (int i = 0; i < 16; i += 4) {
            float p0 = __ocml_native_exp2_f32(sc0[i + 0]);
            float p1 = __ocml_native_exp2_f32(sc0[i + 1]);
            float p2 = __ocml_native_exp2_f32(sc0[i + 2]);
            float p3 = __ocml_native_exp2_f32(sc0[i + 3]);
            sc0[i + 0] = p0; sc0[i + 1] = p1; sc0[i + 2] = p2; sc0[i + 3] = p3;
            ls0 += p0; ls1 += p1; ls2 += p2; ls3 += p3;
        }
        #pragma unroll
        for (int i = 0; i < 16; i += 4) {
            float p0 = __ocml_native_exp2_f32(sc1[i + 0]);
            float p1 = __ocml_native_exp2_f32(sc1[i + 1]);
            float p2 = __ocml_native_exp2_f32(sc1[i + 2]);
            float p3 = __ocml_native_exp2_f32(sc1[i + 3]);
            sc1[i + 0] = p0; sc1[i + 1] = p1; sc1[i + 2] = p2; sc1[i + 3] = p3;
            ls0 += p0; ls1 += p1; ls2 += p2; ls3 += p3;
        }

#define PVSTEP(S, TAU, B8) { \
        union { unsigned u[4]; short8 sv; } pb; \
        pb.u[0] = pkbf(S[B8 + 0], S[B8 + 1]); \
        pb.u[1] = pkbf(S[B8 + 2], S[B8 + 3]); \
        pb.u[2] = pkbf(S[B8 + 4], S[B8 + 5]); \
        pb.u[3] = pkbf(S[B8 + 6], S[B8 + 7]); \
        const int vcs = (((TAU) * 16 + h5 * 8) ^ sw0); \
        short8 vf0 = *(const short8*)&Vb[rb0 + vcs]; \
        short8 vf1 = *(const short8*)&Vb[rb1 + vcs]; \
        o0 = MFMA32(vf0, pb.sv, o0); \
        o1 = MFMA32(vf1, pb.sv, o1); }

        PVSTEP(sc0, 0, 0);
        PVSTEP(sc0, 1, 8);
        PVSTEP(sc1, 2, 0);
        PVSTEP(sc1, 3, 8);
#undef PVSTEP

        if (tile < 15) __syncthreads();
    }

    float l_run = (ls0 + ls1) + (ls2 + ls3);
    float l_tot = l_run + __shfl_xor(l_run, 32);
    float inv = 1.0f / l_tot;

    __syncthreads();
    u16* Ot = &KV[0][0];
    const int bb = bh >> 4, hh = bh & 15;
    const int obase = w * 1280;

    #pragma unroll
    for (int pass = 0; pass < 2; ++pass) {
        #pragma unroll
        for (int r = 0; r < 16; r += 2) {
            int dl = (r & 3) + 8 * (r >> 2) + 4 * h5;
            float a = (pass ? o1[r]     : o0[r])     * inv;
            float b = (pass ? o1[r + 1] : o0[r + 1]) * inv;
            *(unsigned*)&Ot[obase + ql * 40 + dl] = pkbf(a, b);
        }
        __syncthreads();
        #pragma unroll
        for (int i = 0; i < 2; ++i) {
            int dl = h5 * 16 + i * 8;
            short8 vv = *(const short8*)&Ot[obase + ql * 40 + dl];
            int d = pass * 32 + dl;
            *(short8*)&heads[((size_t)(bb * SEQ + q0 + ql) * NH + hh) * HD + d] = vv;
        }
        __syncthreads();
    }
#undef STAGE
}

// ---------------------------------------------------------------------------
extern "C" void kernel_launch(void* const* d_in, const int* in_sizes, int n_in,
                              void* d_out, int out_size, void* d_ws, size_t ws_size,
                              hipStream_t stream) {
    const float* q  = (const float*)d_in[0];
    const float* x  = (const float*)d_in[1];
    const float* Wq = (const float*)d_in[2];
    const float* bq = (const float*)d_in[3];
    const float* Wk = (const float*)d_in[4];
    const float* bk = (const float*)d_in[5];
    const float* Wv = (const float*)d_in[6];
    const float* bv = (const float*)d_in[7];
    const float* Wp = (const float*)d_in[8];
    const float* bp = (const float*)d_in[9];
    float* out = (float*)d_out;

    const size_t SZ = (size_t)MROWS * DIMS;
    const size_t WZ = (size_t)DIMS * DIMS;
    u16* qb  = (u16*)d_ws;
    u16* xb  = qb  + SZ;
    u16* Wqt = xb  + SZ;
    u16* Wkt = Wqt + WZ;
    u16* Wvt = Wkt + WZ;
    u16* Wpt = Wvt + WZ;
    u16* Qm  = Wpt + WZ;
    u16* Km  = Qm  + SZ;
    u16* Vm  = Km  + SZ;
    u16* Hm  = Vm  + SZ;

    const float qscale = 0.125f * 1.4426950408889634f;   // log2 domain

    hipLaunchKernelGGL(convert_both, dim3(8192), dim3(256), 0, stream, q, x, qb, xb);
    hipLaunchKernelGGL(transpose_all, dim3(1024), dim3(256), 0, stream,
                       Wq, Wk, Wv, Wp, Wqt, Wkt, Wvt, Wpt);
    hipLaunchKernelGGL(gemm_qkv, dim3(1536), dim3(256), 0, stream,
                       qb, xb, Wqt, Wkt, Wvt, bq, bk, bv, Qm, Km, Vm, qscale);
    hipLaunchKernelGGL(attn_mfma32_kernel, dim3(512), dim3(512), 0, stream, Qm, Km, Vm, Hm);
    hipLaunchKernelGGL(gemm_out, dim3(512), dim3(256), 0, stream, Hm, Wpt, bp, out);
}

// Round 13
// 158.810 us; speedup vs baseline: 2.1075x; 1.0805x over previous
//
#include <hip/hip_runtime.h>
#include <hip/hip_bf16.h>
#include <math.h>

#define NB   8
#define SEQ  1024
#define DIMS 1024
#define NH   16
#define HD   64
#define MROWS (NB*SEQ)   // 8192

typedef unsigned short u16;
typedef short short8 __attribute__((ext_vector_type(8)));
typedef short short4v __attribute__((ext_vector_type(4)));
typedef float f32x4 __attribute__((ext_vector_type(4)));
typedef float f32x16 __attribute__((ext_vector_type(16)));

extern "C" __device__ float __ocml_native_exp2_f32(float);   // bare v_exp_f32

__device__ inline u16 f2bf(float f) {
    unsigned u = __float_as_uint(f);
    u += 0x7fff + ((u >> 16) & 1);   // RNE
    return (u16)(u >> 16);
}

__device__ inline unsigned pkbf(float a, float b) {
    float2 f2; f2.x = a; f2.y = b;
    __hip_bfloat162 h = __float22bfloat162_rn(f2);
    return *reinterpret_cast<unsigned*>(&h);
}

#define MFMA16(a, b, c) __builtin_amdgcn_mfma_f32_16x16x32_bf16((a), (b), (c), 0, 0, 0)
#define MFMA32(a, b, c) __builtin_amdgcn_mfma_f32_32x32x16_bf16((a), (b), (c), 0, 0, 0)
#define GLD16(g, l) __builtin_amdgcn_global_load_lds( \
    (const __attribute__((address_space(1))) void*)(g), \
    (__attribute__((address_space(3))) void*)(l), 16, 0, 0)

// ---------------------------------------------------------------------------
// fp32 -> bf16 elementwise, q and x in ONE launch
// ---------------------------------------------------------------------------
__global__ __launch_bounds__(256)
void convert_both(const float* __restrict__ qin, const float* __restrict__ xin,
                  u16* __restrict__ qo, u16* __restrict__ xo)
{
    const int half = (MROWS * DIMS / 8) / 256;         // 4096
    const float* in = (blockIdx.x < half) ? qin : xin;
    u16* out        = (blockIdx.x < half) ? qo  : xo;
    int i = (blockIdx.x < half ? blockIdx.x : blockIdx.x - half) * 256 + threadIdx.x;
    float4 v0 = ((const float4*)in)[2 * i];
    float4 v1 = ((const float4*)in)[2 * i + 1];
    union { short8 s; u16 u[8]; } r;
    r.u[0] = f2bf(v0.x); r.u[1] = f2bf(v0.y); r.u[2] = f2bf(v0.z); r.u[3] = f2bf(v0.w);
    r.u[4] = f2bf(v1.x); r.u[5] = f2bf(v1.y); r.u[6] = f2bf(v1.z); r.u[7] = f2bf(v1.w);
    ((short8*)out)[i] = r.s;
}

// ---------------------------------------------------------------------------
// All four W[k][n] fp32 -> Wt[n][k] bf16 transposes in ONE launch
// ---------------------------------------------------------------------------
__global__ __launch_bounds__(256)
void transpose_all(const float* __restrict__ W0, const float* __restrict__ W1,
                   const float* __restrict__ W2, const float* __restrict__ W3,
                   u16* __restrict__ T0, u16* __restrict__ T1o,
                   u16* __restrict__ T2, u16* __restrict__ T3)
{
    __shared__ u16 T[64][72];
    const int which = blockIdx.x >> 8;
    const int idx   = blockIdx.x & 255;
    const float* W = which == 0 ? W0 : which == 1 ? W1 : which == 2 ? W2 : W3;
    u16*        Wt = which == 0 ? T0 : which == 1 ? T1o : which == 2 ? T2 : T3;
    const int t  = threadIdx.x;
    const int k0 = (idx >> 4) * 64;
    const int n0 = (idx & 15) * 64;
    #pragma unroll
    for (int it = 0; it < 4; ++it) {
        int f  = t + it * 256;
        int kl = f >> 4;
        int n4 = (f & 15) * 4;
        float4 v = *(const float4*)&W[(size_t)(k0 + kl) * DIMS + n0 + n4];
        T[n4 + 0][kl] = f2bf(v.x);
        T[n4 + 1][kl] = f2bf(v.y);
        T[n4 + 2][kl] = f2bf(v.z);
        T[n4 + 3][kl] = f2bf(v.w);
    }
    __syncthreads();
    #pragma unroll
    for (int it = 0; it < 2; ++it) {
        int c  = t + it * 256;
        int nl = c >> 3;
        int k8 = (c & 7) * 8;
        *(short8*)&Wt[(size_t)(n0 + nl) * DIMS + k0 + k8] = *(const short8*)&T[nl][k8];
    }
}

// ===========================================================================
// Deep-pipelined GEMM core (shared by gemm_qkv8 / gemm_out8):
// 256x128 tile, BK=64, 512 thr / 8 waves (4M x 2N -> 64x64 per wave).
// Ring-of-3 LDS buffers (48KB each = 144KB): stage target (t+2)%3 is never a
// buffer being read. Per K-tile: 2 fine phases, each {3 global_load_lds for
// t+2 || 8 swizzled ds_read_b128 || 16 MFMA in setprio}, raw s_barrier;
// counted s_waitcnt vmcnt(6) ONCE per tile (t+1's 6 loads retired; t+2's 6
// stay in flight -> ~3 phases of latency cover). T2 XOR swizzle: global
// source chunk kc^(row&7), read offset ^(lo&7)<<3 (same involution).
// ===========================================================================
#define GEMM_CORE(A_, Bt_)                                                     \
    const int lo = lane & 15, hi = lane >> 4;                                  \
    const int wM = w >> 1, wN = w & 1;                                         \
    const u16* gA[4]; const u16* gB[2];                                        \
    _Pragma("unroll")                                                          \
    for (int i = 0; i < 4; ++i) {                                              \
        int c = i * 512 + t, row = c >> 3, kc = c & 7;                         \
        gA[i] = A_ + (size_t)(m0 + row) * 1024 + (kc ^ (row & 7)) * 8;         \
    }                                                                          \
    _Pragma("unroll")                                                          \
    for (int i = 0; i < 2; ++i) {                                              \
        int c = i * 512 + t, row = c >> 3, kc = c & 7;                         \
        gB[i] = Bt_ + (size_t)(n0 + row) * 1024 + (kc ^ (row & 7)) * 8;        \
    }                                                                          \
    int rowA[4], rowB[4];                                                      \
    _Pragma("unroll")                                                          \
    for (int mf = 0; mf < 4; ++mf) rowA[mf] = (wM * 64 + mf * 16 + lo) * 64;   \
    _Pragma("unroll")                                                          \
    for (int nf = 0; nf < 4; ++nf) rowB[nf] = 16384 + (wN * 64 + nf * 16 + lo) * 64; \
    const int ko0 = (hi * 8) ^ ((lo & 7) << 3);                                \
    const int ko1 = (32 + hi * 8) ^ ((lo & 7) << 3);                           \
    f32x4 acc[4][4];                                                           \
    _Pragma("unroll")                                                          \
    for (int mf = 0; mf < 4; ++mf)                                             \
        _Pragma("unroll")                                                      \
        for (int nf = 0; nf < 4; ++nf) acc[mf][nf] = (f32x4){0.f,0.f,0.f,0.f}; \
    /* prologue: stage tiles 0,1 */                                            \
    _Pragma("unroll")                                                          \
    for (int i = 0; i < 4; ++i) GLD16(gA[i],      smem + i * 4096 + w * 512);  \
    _Pragma("unroll")                                                          \
    for (int i = 0; i < 2; ++i) GLD16(gB[i],      smem + 16384 + i * 4096 + w * 512); \
    _Pragma("unroll")                                                          \
    for (int i = 0; i < 4; ++i) GLD16(gA[i] + 64, smem + 24576 + i * 4096 + w * 512); \
    _Pragma("unroll")                                                          \
    for (int i = 0; i < 2; ++i) GLD16(gB[i] + 64, smem + 24576 + 16384 + i * 4096 + w * 512); \
    asm volatile("s_waitcnt vmcnt(6)" ::: "memory");                           \
    __builtin_amdgcn_s_barrier();                                              \
    int b0 = 0, b1 = 24576, b2 = 49152;                                        \
    for (int kt = 0; kt < 16; ++kt) {                                          \
        /* ---- phase 0: stage 3 of tile kt+2, compute s=0 ---- */             \
        if (kt < 14) {                                                         \
            GLD16(gA[0] + (size_t)(kt + 2) * 64, smem + b2 + 0 * 4096 + w * 512);        \
            GLD16(gA[1] + (size_t)(kt + 2) * 64, smem + b2 + 1 * 4096 + w * 512);        \
            GLD16(gB[0] + (size_t)(kt + 2) * 64, smem + b2 + 16384 + 0 * 4096 + w * 512);\
        }                                                                      \
        {                                                                      \
            short8 fa[4], fb[4];                                               \
            _Pragma("unroll")                                                  \
            for (int mf = 0; mf < 4; ++mf) fa[mf] = *(const short8*)&smem[b0 + rowA[mf] + ko0]; \
            _Pragma("unroll")                                                  \
            for (int nf = 0; nf < 4; ++nf) fb[nf] = *(const short8*)&smem[b0 + rowB[nf] + ko0]; \
            __builtin_amdgcn_s_setprio(1);                                     \
            _Pragma("unroll")                                                  \
            for (int mf = 0; mf < 4; ++mf)                                     \
                _Pragma("unroll")                                              \
                for (int nf = 0; nf < 4; ++nf)                                 \
                    acc[mf][nf] = MFMA16(fa[mf], fb[nf], acc[mf][nf]);         \
            __builtin_amdgcn_s_setprio(0);                                     \
        }                                                                      \
        __builtin_amdgcn_s_barrier();                                          \
        /* ---- phase 1: stage rest of tile kt+2, compute s=1 ---- */          \
        if (kt < 14) {                                                         \
            GLD16(gA[2] + (size_t)(kt + 2) * 64, smem + b2 + 2 * 4096 + w * 512);        \
            GLD16(gA[3] + (size_t)(kt + 2) * 64, smem + b2 + 3 * 4096 + w * 512);        \
            GLD16(gB[1] + (size_t)(kt + 2) * 64, smem + b2 + 16384 + 1 * 4096 + w * 512);\
        }                                                                      \
        {                                                                      \
            short8 fa[4], fb[4];                                               \
            _Pragma("unroll")                                                  \
            for (int mf = 0; mf < 4; ++mf) fa[mf] = *(const short8*)&smem[b0 + rowA[mf] + ko1]; \
            _Pragma("unroll")                                                  \
            for (int nf = 0; nf < 4; ++nf) fb[nf] = *(const short8*)&smem[b0 + rowB[nf] + ko1]; \
            __builtin_amdgcn_s_setprio(1);                                     \
            _Pragma("unroll")                                                  \
            for (int mf = 0; mf < 4; ++mf)                                     \
                _Pragma("unroll")                                              \
                for (int nf = 0; nf < 4; ++nf)                                 \
                    acc[mf][nf] = MFMA16(fa[mf], fb[nf], acc[mf][nf]);         \
            __builtin_amdgcn_s_setprio(0);                                     \
        }                                                                      \
        if (kt < 14) { asm volatile("s_waitcnt vmcnt(6)" ::: "memory"); }      \
        else         { asm volatile("s_waitcnt vmcnt(0)" ::: "memory"); }      \
        __builtin_amdgcn_s_barrier();                                          \
        int tmp = b0; b0 = b1; b1 = b2; b2 = tmp;                              \
    }

// ---------------------------------------------------------------------------
// FUSED Q/K/V projection GEMM, deep-pipelined. Grid 768 = 3 x (32 bm x 8 bn).
// which 0: Qm=(qb@Wq+bq)*qscale -> [b][h][p][d]; 1: Km; 2: Vm -> [b][h][d][p]
// kv-pi-permuted. Dynamic LDS 144KB (ring) reused as epilogue scratch.
// ---------------------------------------------------------------------------
__global__ __launch_bounds__(512, 2)
void gemm_qkv8(const u16* __restrict__ qb, const u16* __restrict__ xb,
               const u16* __restrict__ Wqt, const u16* __restrict__ Wkt,
               const u16* __restrict__ Wvt,
               const float* __restrict__ bq, const float* __restrict__ bk,
               const float* __restrict__ bv,
               u16* __restrict__ Qm, u16* __restrict__ Km, u16* __restrict__ Vm,
               float qscale)
{
    extern __shared__ u16 smem[];
    const int t = threadIdx.x;
    const int w = t >> 6, lane = t & 63;

    const int wg   = blockIdx.x;
    const int swzb = (wg & 7) * 96 + (wg >> 3);      // T1: 96 ids/XCD, bijective
    const int which = swzb >> 8;
    const int rem   = swzb & 255;
    const int bn = rem & 7, bm = rem >> 3;
    const int m0 = bm * 256, n0 = bn * 128;

    const u16* A      = which == 0 ? qb  : xb;
    const u16* Bt     = which == 0 ? Wqt : which == 1 ? Wkt : Wvt;
    const float* bias = which == 0 ? bq : which == 1 ? bk : bv;
    const float scale = which == 0 ? qscale : 1.0f;

    GEMM_CORE(A, Bt)

    // ---- epilogue: reuse smem as scratch ----
    __syncthreads();
    const int bb = m0 >> 10, p0 = m0 & 1023;
    if (which < 2) {
        u16* out = which == 0 ? Qm : Km;
        #pragma unroll
        for (int mf = 0; mf < 4; ++mf)
            #pragma unroll
            for (int j = 0; j < 4; ++j) {
                int pl = wM * 64 + mf * 16 + hi * 4 + j;       // 0..255
                #pragma unroll
                for (int nf = 0; nf < 4; ++nf) {
                    int nl = wN * 64 + nf * 16 + lo;           // 0..127
                    int h = nl & 15, dl = nl >> 4;
                    float v = (acc[mf][nf][j] + bias[n0 + nl]) * scale;
                    smem[pl * 136 + h * 8 + dl] = f2bf(v);
                }
            }
        __syncthreads();
        const int dg = n0 >> 4;
        #pragma unroll
        for (int it = 0; it < 8; ++it) {
            int c = t + it * 512;              // 0..4095
            int h = c & 15, pl = c >> 4;       // pl 0..255
            u16* dst = out + ((size_t)((bb * NH + h) * SEQ + p0 + pl)) * HD + dg;
            *(short8*)dst = *(const short8*)&smem[pl * 136 + h * 8];
        }
    } else {
        #pragma unroll
        for (int mf = 0; mf < 4; ++mf)
            #pragma unroll
            for (int j = 0; j < 4; ++j) {
                int pl = wM * 64 + mf * 16 + hi * 4 + j;
                #pragma unroll
                for (int nf = 0; nf < 4; ++nf) {
                    int nl = wN * 64 + nf * 16 + lo;
                    smem[nl * 264 + pl] = f2bf(acc[mf][nf][j] + bias[n0 + nl]);
                }
            }
        __syncthreads();
        #pragma unroll
        for (int it = 0; it < 8; ++it) {
            int c  = t + it * 512;             // 0..4095
            int nl = c >> 5, p8 = c & 31;      // nl 0..127, p8 0..31
            int ng = n0 + nl;
            int h = ng & 15, d = ng >> 4;
            u16* dstrow = Vm + ((size_t)((bb * NH + h) * HD + d)) * SEQ + p0;
            const u16* src = &smem[nl * 264 + p8 * 8];
            int base16 = (p8 >> 1) * 16, c8 = p8 & 1;
            *(short4v*)&dstrow[base16 + c8 * 4]     = *(const short4v*)&src[0];
            *(short4v*)&dstrow[base16 + c8 * 4 + 8] = *(const short4v*)&src[4];
        }
    }
}

// ---------------------------------------------------------------------------
// Final projection GEMM, deep-pipelined, fp32 output. Grid 256 = 32 x 8.
// ---------------------------------------------------------------------------
__global__ __launch_bounds__(512, 2)
void gemm_out8(const u16* __restrict__ Am, const u16* __restrict__ Btm,
               const float* __restrict__ bias, float* __restrict__ out)
{
    extern __shared__ u16 smem[];
    const int t = threadIdx.x;
    const int w = t >> 6, lane = t & 63;

    const int wg   = blockIdx.x;
    const int swzb = (wg & 7) * 32 + (wg >> 3);
    const int bn = swzb & 7, bm = swzb >> 3;
    const int m0 = bm * 256, n0 = bn * 128;

    GEMM_CORE(Am, Btm)

    #pragma unroll
    for (int mf = 0; mf < 4; ++mf)
        #pragma unroll
        for (int j = 0; j < 4; ++j) {
            int r = m0 + wM * 64 + mf * 16 + hi * 4 + j;
            #pragma unroll
            for (int nf = 0; nf < 4; ++nf) {
                int cc = n0 + wN * 64 + nf * 16 + lo;
                out[(size_t)r * 1024 + cc] = acc[mf][nf][j] + bias[cc];
            }
        }
}

// ---------------------------------------------------------------------------
// LDS-staged swapped-operand 32x32x16 MFMA flash attention (r9 version).
// ---------------------------------------------------------------------------
__global__ __launch_bounds__(512, 4)
void attn_mfma32_kernel(const u16* __restrict__ Qm, const u16* __restrict__ Km,
                        const u16* __restrict__ Vp, u16* __restrict__ heads)
{
    __shared__ u16 KV[2][8192];   // [buf][ K:0..4095 | V:4096..8191 ]  32KB

    const int t  = threadIdx.x;          // 0..511
    const int w  = t >> 6, lane = t & 63;
    const int ql = lane & 31, h5 = lane >> 5;

    const int wg  = blockIdx.x;
    const int swz = (wg & 7) * 64 + (wg >> 3);
    const int qb  = swz & 3;
    const int bh  = swz >> 2;
    const int q0  = qb * 256 + w * 32;
    const size_t kbase = (size_t)bh * (SEQ * HD);
    const size_t vbase = (size_t)bh * (HD * SEQ);

    const int lc = t ^ ((t >> 3) & 7);
    const u16* gK = Km + kbase + (size_t)lc * 8;
    const u16* gV = Vp + vbase + (size_t)(t >> 3) * SEQ + (lc & 7) * 8;
    const int ldK = w * 512;
    const int ldV = 4096 + w * 512;

#define STAGE(B, T) do { \
    GLD16(gK + (size_t)(T) * 4096, &KV[B][ldK]); \
    GLD16(gV + (T) * 64,           &KV[B][ldV]); } while (0)

    STAGE(0, 0);

    short8 qf[4];
    #pragma unroll
    for (int td = 0; td < 4; ++td)
        qf[td] = *(const short8*)&Qm[kbase + (size_t)(q0 + ql) * HD + td * 16 + h5 * 8];

    const int sw0 = (ql & 7) << 3;
    const int rb0 = ql * 64, rb1 = (32 + ql) * 64;
    int kof[4];
    #pragma unroll
    for (int i = 0; i < 4; ++i)
        kof[i] = (i * 16 + h5 * 8) ^ sw0;

    f32x16 o0, o1;
    #pragma unroll
    for (int i = 0; i < 16; ++i) { o0[i] = 0.f; o1[i] = 0.f; }
    float ls0 = 0.f, ls1 = 0.f, ls2 = 0.f, ls3 = 0.f;

    __syncthreads();

    for (int tile = 0; tile < 16; ++tile) {
        const int buf = tile & 1;
        if (tile < 15) STAGE(buf ^ 1, tile + 1);

        const u16* Kb = &KV[buf][0];
        const u16* Vb = &KV[buf][4096];

        f32x16 sc0, sc1;
        #pragma unroll
        for (int i = 0; i < 16; ++i) { sc0[i] = 0.f; sc1[i] = 0.f; }
        {
            short8 k0 = *(const short8*)&Kb[rb0 + kof[0]];
            short8 k1 = *(const short8*)&Kb[rb0 + kof[1]];
            short8 k2 = *(const short8*)&Kb[rb0 + kof[2]];
            short8 k3 = *(const short8*)&Kb[rb0 + kof[3]];
            sc0 = MFMA32(k0, qf[0], sc0);
            sc0 = MFMA32(k1, qf[1], sc0);
            sc0 = MFMA32(k2, qf[2], sc0);
            sc0 = MFMA32(k3, qf[3], sc0);
            short8 m0_ = *(const short8*)&Kb[rb1 + kof[0]];
            short8 m1_ = *(const short8*)&Kb[rb1 + kof[1]];
            short8 m2_ = *(const short8*)&Kb[rb1 + kof[2]];
            short8 m3_ = *(const short8*)&Kb[rb1 + kof[3]];
            sc1 = MFMA32(m0_, qf[0], sc1);
            sc1 = MFMA32(m1_, qf[1], sc1);
            sc1 = MFMA32(m2_, qf[2], sc1);
            sc1 = MFMA32(m3_, qf[3], sc1);
        }

        #pragma unroll
        for (int i = 0; i < 16; i += 4) {
            float p0 = __ocml_native_exp2_f32(sc0[i + 0]);
            float p1 = __ocml_native_exp2_f32(sc0[i + 1]);
            float p2 = __ocml_native_exp2_f32(sc0[i + 2]);
            float p3 = __ocml_native_exp2_f32(sc0[i + 3]);
            sc0[i + 0] = p0; sc0[i + 1] = p1; sc0[i + 2] = p2; sc0[i + 3] = p3;
            ls0 += p0; ls1 += p1; ls2 += p2; ls3 += p3;
        }
        #pragma unroll
        for (int i = 0; i < 16; i += 4) {
            float p0 = __ocml_native_exp2_f32(sc1[i + 0]);
            float p1 = __ocml_native_exp2_f32(sc1[i + 1]);
            float p2 = __ocml_native_exp2_f32(sc1[i + 2]);
            float p3 = __ocml_native_exp2_f32(sc1[i + 3]);
            sc1[i + 0] = p0; sc1[i + 1] = p1; sc1[i + 2] = p2; sc1[i + 3] = p3;
            ls0 += p0; ls1 += p1; ls2 += p2; ls3 += p3;
        }

#define PVSTEP(S, TAU, B8) { \
        union { unsigned u[4]; short8 sv; } pb; \
        pb.u[0] = pkbf(S[B8 + 0], S[B8 + 1]); \
        pb.u[1] = pkbf(S[B8 + 2], S[B8 + 3]); \
        pb.u[2] = pkbf(S[B8 + 4], S[B8 + 5]); \
        pb.u[3] = pkbf(S[B8 + 6], S[B8 + 7]); \
        const int vcs = (((TAU) * 16 + h5 * 8) ^ sw0); \
        short8 vf0 = *(const short8*)&Vb[rb0 + vcs]; \
        short8 vf1 = *(const short8*)&Vb[rb1 + vcs]; \
        o0 = MFMA32(vf0, pb.sv, o0); \
        o1 = MFMA32(vf1, pb.sv, o1); }

        PVSTEP(sc0, 0, 0);
        PVSTEP(sc0, 1, 8);
        PVSTEP(sc1, 2, 0);
        PVSTEP(sc1, 3, 8);
#undef PVSTEP

        if (tile < 15) __syncthreads();
    }

    float l_run = (ls0 + ls1) + (ls2 + ls3);
    float l_tot = l_run + __shfl_xor(l_run, 32);
    float inv = 1.0f / l_tot;

    __syncthreads();
    u16* Ot = &KV[0][0];
    const int bb = bh >> 4, hh = bh & 15;
    const int obase = w * 1280;

    #pragma unroll
    for (int pass = 0; pass < 2; ++pass) {
        #pragma unroll
        for (int r = 0; r < 16; r += 2) {
            int dl = (r & 3) + 8 * (r >> 2) + 4 * h5;
            float a = (pass ? o1[r]     : o0[r])     * inv;
            float b = (pass ? o1[r + 1] : o0[r + 1]) * inv;
            *(unsigned*)&Ot[obase + ql * 40 + dl] = pkbf(a, b);
        }
        __syncthreads();
        #pragma unroll
        for (int i = 0; i < 2; ++i) {
            int dl = h5 * 16 + i * 8;
            short8 vv = *(const short8*)&Ot[obase + ql * 40 + dl];
            int d = pass * 32 + dl;
            *(short8*)&heads[((size_t)(bb * SEQ + q0 + ql) * NH + hh) * HD + d] = vv;
        }
        __syncthreads();
    }
#undef STAGE
}

// ---------------------------------------------------------------------------
extern "C" void kernel_launch(void* const* d_in, const int* in_sizes, int n_in,
                              void* d_out, int out_size, void* d_ws, size_t ws_size,
                              hipStream_t stream) {
    const float* q  = (const float*)d_in[0];
    const float* x  = (const float*)d_in[1];
    const float* Wq = (const float*)d_in[2];
    const float* bq = (const float*)d_in[3];
    const float* Wk = (const float*)d_in[4];
    const float* bk = (const float*)d_in[5];
    const float* Wv = (const float*)d_in[6];
    const float* bv = (const float*)d_in[7];
    const float* Wp = (const float*)d_in[8];
    const float* bp = (const float*)d_in[9];
    float* out = (float*)d_out;

    const size_t SZ = (size_t)MROWS * DIMS;
    const size_t WZ = (size_t)DIMS * DIMS;
    u16* qb  = (u16*)d_ws;
    u16* xb  = qb  + SZ;
    u16* Wqt = xb  + SZ;
    u16* Wkt = Wqt + WZ;
    u16* Wvt = Wkt + WZ;
    u16* Wpt = Wvt + WZ;
    u16* Qm  = Wpt + WZ;
    u16* Km  = Qm  + SZ;
    u16* Vm  = Km  + SZ;
    u16* Hm  = Vm  + SZ;

    const float qscale = 0.125f * 1.4426950408889634f;   // log2 domain
    const int LDS_BYTES = 147456;                        // 3 x 48KB ring

    // best-effort opt-in for >64KB dynamic LDS (no-op if already allowed)
    hipFuncSetAttribute((const void*)gemm_qkv8,
                        hipFuncAttributeMaxDynamicSharedMemorySize, LDS_BYTES);
    hipFuncSetAttribute((const void*)gemm_out8,
                        hipFuncAttributeMaxDynamicSharedMemorySize, LDS_BYTES);

    hipLaunchKernelGGL(convert_both, dim3(8192), dim3(256), 0, stream, q, x, qb, xb);
    hipLaunchKernelGGL(transpose_all, dim3(1024), dim3(256), 0, stream,
                       Wq, Wk, Wv, Wp, Wqt, Wkt, Wvt, Wpt);
    hipLaunchKernelGGL(gemm_qkv8, dim3(768), dim3(512), LDS_BYTES, stream,
                       qb, xb, Wqt, Wkt, Wvt, bq, bk, bv, Qm, Km, Vm, qscale);
    hipLaunchKernelGGL(attn_mfma32_kernel, dim3(512), dim3(512), 0, stream, Qm, Km, Vm, Hm);
    hipLaunchKernelGGL(gemm_out8, dim3(256), dim3(512), LDS_BYTES, stream, Hm, Wpt, bp, out);
}